// Round 4
// baseline (18356.337 us; speedup 1.0000x reference)
//
#include <hip/hip_runtime.h>
#include <hip/hip_bf16.h>

typedef __attribute__((ext_vector_type(8))) short bf16x8;
typedef __attribute__((ext_vector_type(4))) float f32x4;

__device__ inline unsigned short f2b(float x){
  union { float f; unsigned int u; } v; v.f = x;
  unsigned int u = v.u;
  return (unsigned short)((u + 0x7FFFu + ((u >> 16) & 1u)) >> 16);
}
__device__ inline float b2f(unsigned short h){
  union { unsigned int u; float f; } v; v.u = ((unsigned int)h) << 16; return v.f;
}
__device__ inline float sigm(float x){ return 1.f / (1.f + __expf(-x)); }
__device__ inline float tanh_f(float x){ float e2 = __expf(2.f * x); return 1.f - 2.f / (e2 + 1.f); }

__global__ __launch_bounds__(256) void zerofill(float* __restrict__ p, int n){
  int i = blockIdx.x * 256 + threadIdx.x;
  if (i < n) p[i] = 0.f;
}

// packed row for gate-row n = g*1024 + h:  blk = h>>3, local = (h&7)*4 + g
__device__ inline int packrow(int n){
  int g = n >> 10, h = n & 1023;
  return (h >> 3) * 32 + (h & 7) * 4 + g;
}

// ---- prep: Wsum packed (for persistent), Whh plain bf16 (for step0), biases ----
__global__ __launch_bounds__(256) void prep_w(
    const float* __restrict__ Wih, const float* __restrict__ Whh,
    const float* __restrict__ bih, const float* __restrict__ bhh,
    unsigned short* __restrict__ Wsum_p, unsigned short* __restrict__ Whh_b,
    float* __restrict__ bias_sp)
{
  size_t idx = (size_t)blockIdx.x * 256 + threadIdx.x; // 4096*1024
  int r = (int)(idx >> 10), k = (int)(idx & 1023);
  float wi = Wih[idx], wh = Whh[idx];
  Wsum_p[(size_t)packrow(r) * 1024 + k] = f2b(wi + wh);
  Whh_b[idx] = f2b(wh);
  if (idx < 4096) bias_sp[packrow((int)idx)] = bih[idx] + bhh[idx];
}

// bias0[n] (plain) = bih+bhh + sum_k W_ih[n,k]*go[0,k]
__global__ __launch_bounds__(256) void prep_b0(
    const float* __restrict__ Wih, const float* __restrict__ go,
    const float* __restrict__ bih, const float* __restrict__ bhh,
    float* __restrict__ bias0)
{
  __shared__ float red[4];
  int n = blockIdx.x, t = threadIdx.x;
  float acc = 0.f;
  for (int k = t; k < 1024; k += 256) acc += Wih[(size_t)n*1024 + k] * go[k];
  for (int off = 32; off > 0; off >>= 1) acc += __shfl_down(acc, off, 64);
  if ((t & 63) == 0) red[t >> 6] = acc;
  __syncthreads();
  if (t == 0) bias0[n] = bih[n] + bhh[n] + red[0] + red[1] + red[2] + red[3];
}

// ---- z projections (K=128, f32) ----
__global__ __launch_bounds__(256) void zproj(
    const float* __restrict__ z, const float* __restrict__ Wzh, const float* __restrict__ bzh,
    const float* __restrict__ Wzc, const float* __restrict__ bzc,
    float* __restrict__ zh_raw, float* __restrict__ zc_raw)
{
  int idx = blockIdx.x * 256 + threadIdx.x; // 256*1024
  int b = idx >> 10, c = idx & 1023;
  const float* zr = z + b * 128;
  const float* wh = Wzh + c * 128;
  const float* wc = Wzc + c * 128;
  float s1 = bzh[c], s2 = bzc[c];
  #pragma unroll 8
  for (int k = 0; k < 128; k++){ float zv = zr[k]; s1 += zv * wh[k]; s2 += zv * wc[k]; }
  zh_raw[idx] = s1; zc_raw[idx] = s2;
}

// ---- BN over batch: zh -> zh_b (bf16), zc -> c_f (f32) ----
__global__ __launch_bounds__(256) void bn_init(
    const float* __restrict__ zh_raw, const float* __restrict__ zc_raw,
    const float* __restrict__ g_h, const float* __restrict__ bt_h,
    const float* __restrict__ g_c, const float* __restrict__ bt_c,
    unsigned short* __restrict__ zh_b, float* __restrict__ c_f)
{
  __shared__ float red[4][4];
  int c = blockIdx.x, r = threadIdx.x;
  float v1 = zh_raw[r * 1024 + c];
  float v2 = zc_raw[r * 1024 + c];
  float s[4] = { v1, v1*v1, v2, v2*v2 };
  #pragma unroll
  for (int i = 0; i < 4; i++){
    float x = s[i];
    for (int off = 32; off > 0; off >>= 1) x += __shfl_down(x, off, 64);
    if ((r & 63) == 0) red[i][r >> 6] = x;
  }
  __syncthreads();
  float m1 = (red[0][0]+red[0][1]+red[0][2]+red[0][3]) * (1.f/256.f);
  float q1 = (red[1][0]+red[1][1]+red[1][2]+red[1][3]) * (1.f/256.f);
  float m2 = (red[2][0]+red[2][1]+red[2][2]+red[2][3]) * (1.f/256.f);
  float q2 = (red[3][0]+red[3][1]+red[3][2]+red[3][3]) * (1.f/256.f);
  float var1 = q1 - m1*m1; if (var1 < 0.f) var1 = 0.f;
  float var2 = q2 - m2*m2; if (var2 < 0.f) var2 = 0.f;
  float a1 = g_h[c] * rsqrtf(var1 + 1e-5f), be1 = bt_h[c] - m1*a1;
  float a2 = g_c[c] * rsqrtf(var2 + 1e-5f), be2 = bt_c[c] - m2*a2;
  zh_b[r * 1024 + c] = f2b(v1*a1 + be1);
  c_f[r * 1024 + c] = v2*a2 + be2;
}

// ---- MLP / step0 GEMM: out[M][N] = A[M][K] @ B[N][K]^T + bias; 64x128 tile ----
template<int K, int ACT, int OBF16>
__global__ __launch_bounds__(256) void gemm_bt2(
    const unsigned short* __restrict__ A, const unsigned short* __restrict__ B,
    const float* __restrict__ bias, void* __restrict__ outp, int N)
{
  const int tid = threadIdx.x;
  const int w = tid >> 6, l = tid & 63;
  const int lr = l & 15, lg = l >> 4;
  const int m0 = blockIdx.y * 64 + (w >> 1) * 32;
  const int n0 = blockIdx.x * 128 + (w & 1) * 64;
  f32x4 acc[2][4];
  #pragma unroll
  for (int i = 0; i < 2; i++)
    #pragma unroll
    for (int j = 0; j < 4; j++) acc[i][j] = (f32x4){0.f,0.f,0.f,0.f};

  const unsigned short* pa0 = A + (size_t)(m0 + lr) * K + lg * 8;
  const unsigned short* pa1 = pa0 + (size_t)16 * K;
  const unsigned short* pb0 = B + (size_t)(n0 + lr) * K + lg * 8;

  for (int kb = 0; kb < K; kb += 32){
    bf16x8 a0 = *(const bf16x8*)(pa0 + kb);
    bf16x8 a1 = *(const bf16x8*)(pa1 + kb);
    bf16x8 b0 = *(const bf16x8*)(pb0 + kb);
    bf16x8 b1 = *(const bf16x8*)(pb0 + (size_t)16 * K + kb);
    bf16x8 b2 = *(const bf16x8*)(pb0 + (size_t)32 * K + kb);
    bf16x8 b3 = *(const bf16x8*)(pb0 + (size_t)48 * K + kb);
    acc[0][0] = __builtin_amdgcn_mfma_f32_16x16x32_bf16(a0, b0, acc[0][0], 0, 0, 0);
    acc[0][1] = __builtin_amdgcn_mfma_f32_16x16x32_bf16(a0, b1, acc[0][1], 0, 0, 0);
    acc[0][2] = __builtin_amdgcn_mfma_f32_16x16x32_bf16(a0, b2, acc[0][2], 0, 0, 0);
    acc[0][3] = __builtin_amdgcn_mfma_f32_16x16x32_bf16(a0, b3, acc[0][3], 0, 0, 0);
    acc[1][0] = __builtin_amdgcn_mfma_f32_16x16x32_bf16(a1, b0, acc[1][0], 0, 0, 0);
    acc[1][1] = __builtin_amdgcn_mfma_f32_16x16x32_bf16(a1, b1, acc[1][1], 0, 0, 0);
    acc[1][2] = __builtin_amdgcn_mfma_f32_16x16x32_bf16(a1, b2, acc[1][2], 0, 0, 0);
    acc[1][3] = __builtin_amdgcn_mfma_f32_16x16x32_bf16(a1, b3, acc[1][3], 0, 0, 0);
  }

  #pragma unroll
  for (int mi = 0; mi < 2; mi++)
    #pragma unroll
    for (int ni = 0; ni < 4; ni++){
      int col = n0 + ni * 16 + lr;
      float bs = bias[col];
      #pragma unroll
      for (int j = 0; j < 4; j++){
        int row = m0 + mi * 16 + lg * 4 + j;
        float v = acc[mi][ni][j] + bs;
        if (ACT) v = v > 0.f ? v : 0.01f * v;
        if (OBF16) ((unsigned short*)outp)[(size_t)row * N + col] = f2b(v);
        else       ((float*)outp)[(size_t)row * N + col] = v;
      }
    }
}

// ---- step-0 cell: gates0 -> c, h(0) (hbuf0), ys[:, :, 0] ----
__global__ __launch_bounds__(256) void lstm_cell0(
    const float* __restrict__ gates, float* __restrict__ c,
    unsigned short* __restrict__ hbuf0, unsigned short* __restrict__ ys)
{
  int idx = blockIdx.x * 256 + threadIdx.x; // 256*1024
  int b = idx >> 10, h = idx & 1023;
  const float* g = gates + (size_t)b * 4096;
  float ig = g[h], fg = g[1024 + h], gg = g[2048 + h], og = g[3072 + h];
  float co = c[idx];
  float c2 = sigm(fg) * co + sigm(ig) * tanh_f(gg);
  float h2 = sigm(og) * tanh_f(c2);
  c[idx] = c2;
  unsigned short hb = f2b(h2);
  hbuf0[idx] = hb;
  ys[(size_t)idx * 256] = hb;   // ys[b][h][t=0]
}

// ---- persistent LSTM: steps 1..255, grid barrier, W in LDS, c in regs ----
// 128 blocks x 512 threads. Block blk owns h-cols [blk*8, blk*8+8) = 32 packed rows.
__global__ __launch_bounds__(512, 1) void lstm_persist(
    const unsigned short* __restrict__ Wp, const float* __restrict__ bias_sp,
    unsigned short* __restrict__ hbuf0, unsigned short* __restrict__ hbuf1,
    const float* __restrict__ c_init, unsigned short* __restrict__ ys,
    unsigned int* __restrict__ bar)
{
  __shared__ unsigned short Wl[32768]; // 64 KB, XOR-swizzled rows of 2048 B
  const int tid = threadIdx.x;
  const int blk = blockIdx.x;
  const int w = tid >> 6, l = tid & 63;
  const int lr = l & 15, lg = l >> 4;

  // stage W slice (32 rows x 1024 bf16) into LDS, swizzled
  for (int i = tid; i < 4096; i += 512){
    int row = i >> 7, ch = i & 127;
    bf16x8 v = *(const bf16x8*)(Wp + (size_t)(blk * 32 + row) * 1024 + ch * 8);
    int byteoff = row * 2048 + ((ch * 16) ^ ((row & 7) << 4));
    *(bf16x8*)((char*)Wl + byteoff) = v;
  }

  const int hw0 = lr >> 2;
  float bb[2];
  bb[0] = bias_sp[blk * 32 + lr];
  bb[1] = bias_sp[blk * 32 + 16 + lr];

  float creg[2][2][4];
  #pragma unroll
  for (int mi = 0; mi < 2; mi++)
    #pragma unroll
    for (int ni = 0; ni < 2; ni++)
      #pragma unroll
      for (int j = 0; j < 4; j++){
        int row = w * 32 + mi * 16 + lg * 4 + j;
        int h = blk * 8 + ni * 4 + hw0;
        creg[mi][ni][j] = c_init[(size_t)row * 1024 + h];
      }

  __syncthreads();

  const int sw = (lr & 7) << 4;
  const char* lb0 = (const char*)Wl + lr * 2048;
  const char* lb1 = (const char*)Wl + (16 + lr) * 2048;

  #pragma unroll 1
  for (int t = 1; t < 256; t++){
    const unsigned short* hin  = (t & 1) ? hbuf0 : hbuf1;
    unsigned short*       hout = (t & 1) ? hbuf1 : hbuf0;

    f32x4 acc[2][2];
    #pragma unroll
    for (int i = 0; i < 2; i++)
      #pragma unroll
      for (int j = 0; j < 2; j++) acc[i][j] = (f32x4){0.f,0.f,0.f,0.f};

    const unsigned short* pa0 = hin + (size_t)(w * 32 + lr) * 1024 + lg * 8;
    const unsigned short* pa1 = pa0 + 16 * 1024;

    #pragma unroll 4
    for (int kb = 0; kb < 1024; kb += 32){
      bf16x8 a0 = *(const bf16x8*)(pa0 + kb);
      bf16x8 a1 = *(const bf16x8*)(pa1 + kb);
      int ko = (kb * 2 + lg * 16) ^ sw;
      bf16x8 b0 = *(const bf16x8*)(lb0 + ko);
      bf16x8 b1 = *(const bf16x8*)(lb1 + ko);
      acc[0][0] = __builtin_amdgcn_mfma_f32_16x16x32_bf16(a0, b0, acc[0][0], 0, 0, 0);
      acc[0][1] = __builtin_amdgcn_mfma_f32_16x16x32_bf16(a0, b1, acc[0][1], 0, 0, 0);
      acc[1][0] = __builtin_amdgcn_mfma_f32_16x16x32_bf16(a1, b0, acc[1][0], 0, 0, 0);
      acc[1][1] = __builtin_amdgcn_mfma_f32_16x16x32_bf16(a1, b1, acc[1][1], 0, 0, 0);
    }

    // cell epilogue: reunite 4 gates across the 4 gate-lanes (lr&3)
    #pragma unroll
    for (int mi = 0; mi < 2; mi++)
      #pragma unroll
      for (int ni = 0; ni < 2; ni++)
        #pragma unroll
        for (int j = 0; j < 4; j++){
          float v = acc[mi][ni][j] + bb[ni];
          float va = v;
          float vb = __shfl_xor(v, 1);
          float vc = __shfl_xor(v, 2);
          float vd = __shfl_xor(vb, 2);
          bool s1 = (lr & 1), s2 = (lr & 2);
          float P1 = s2 ? vc : va, P2 = s2 ? vd : vb;
          float Q1 = s2 ? va : vc, Q2 = s2 ? vb : vd;
          float gi  = s1 ? P2 : P1;
          float gf  = s1 ? P1 : P2;
          float gg  = s1 ? Q2 : Q1;
          float go_ = s1 ? Q1 : Q2;
          float c2 = sigm(gf) * creg[mi][ni][j] + sigm(gi) * tanh_f(gg);
          float h2 = sigm(go_) * tanh_f(c2);
          creg[mi][ni][j] = c2;
          unsigned short hb = f2b(h2);
          int row = w * 32 + mi * 16 + lg * 4 + j;
          int h = blk * 8 + ni * 4 + hw0;
          if ((lr & 3) == 0) ys[((size_t)row * 1024 + h) * 256 + t] = hb;
          if ((lr & 3) == 1) hout[(size_t)row * 1024 + h] = hb;
        }

    if (t < 255){
      __threadfence();      // release: drain my stores, wb L2
      __syncthreads();      // all waves' fences done
      if (tid == 0){
        atomicAdd(bar, 1u);
        unsigned tgt = (unsigned)t * 128u;
        while (atomicAdd(bar, 0u) < tgt) __builtin_amdgcn_s_sleep(2);
      }
      __syncthreads();
      __threadfence();      // acquire: invalidate stale lines before next A-read
    }
  }
}

// ---- column stats (sum, sumsq), stage 1 ----
template<int C>
__global__ __launch_bounds__(256) void stats1(
    const unsigned short* __restrict__ X, float* __restrict__ psum, float* __restrict__ psq)
{
  int col = blockIdx.x * 256 + threadIdx.x;
  int r0 = blockIdx.y * 256;
  float s = 0.f, q = 0.f;
  for (int r = r0; r < r0 + 256; r++){
    float v = b2f(X[(size_t)r * C + col]);
    s += v; q += v * v;
  }
  psum[(size_t)blockIdx.y * C + col] = s;
  psq [(size_t)blockIdx.y * C + col] = q;
}

__global__ __launch_bounds__(256) void stats2(
    const float* __restrict__ psum, const float* __restrict__ psq,
    const float* __restrict__ g, const float* __restrict__ b,
    float* __restrict__ alpha, float* __restrict__ beta, int C)
{
  int c = blockIdx.x * 256 + threadIdx.x;
  if (c >= C) return;
  float s = 0.f, q = 0.f;
  for (int i = 0; i < 256; i++){ s += psum[(size_t)i * C + c]; q += psq[(size_t)i * C + c]; }
  float m = s * (1.f / 65536.f);
  float var = q * (1.f / 65536.f) - m * m; if (var < 0.f) var = 0.f;
  float a = g[c] * rsqrtf(var + 1e-5f);
  alpha[c] = a; beta[c] = b[c] - m * a;
}

// ---- fold BN into weights ----
template<int K>
__global__ __launch_bounds__(256) void foldk(
    const float* __restrict__ W, const float* __restrict__ bias,
    const float* __restrict__ alpha, const float* __restrict__ beta,
    unsigned short* __restrict__ Wb, float* __restrict__ bp, int rows)
{
  __shared__ float red[4];
  int o = blockIdx.x, t = threadIdx.x;
  float acc = 0.f;
  if (o < rows){
    for (int j = t; j < K; j += 256){
      float wv = W[(size_t)o * K + j];
      acc += beta[j] * wv;
      Wb[(size_t)o * K + j] = f2b(wv * alpha[j]);
    }
  } else {
    for (int j = t; j < K; j += 256) Wb[(size_t)o * K + j] = 0;
  }
  for (int off = 32; off > 0; off >>= 1) acc += __shfl_down(acc, off, 64);
  if ((t & 63) == 0) red[t >> 6] = acc;
  __syncthreads();
  if (t == 0) bp[o] = (o < rows ? bias[o] : 0.f) + red[0] + red[1] + red[2] + red[3];
}

// ---- final softmax with raw-reshape index mixing ----
__global__ __launch_bounds__(256) void softmax_k(
    const unsigned short* __restrict__ o3p, float* __restrict__ out)
{
  __shared__ unsigned short tile[25600];
  int b = blockIdx.x, t = threadIdx.x;
  const unsigned short* src = o3p + (size_t)b * 256 * 128;
  for (int i = t; i < 25600; i += 256){
    int rr = i / 100, nc = i - rr * 100;
    tile[i] = src[rr * 128 + nc];
  }
  __syncthreads();
  int v = t;
  float mx = -1e30f;
  for (int u = 0; u < 100; u++) mx = fmaxf(mx, b2f(tile[u * 256 + v]));
  float s = 0.f;
  for (int u = 0; u < 100; u++) s += __expf(b2f(tile[u * 256 + v]) - mx);
  float inv = 1.f / s;
  float* dst = out + (size_t)b * 25600;
  for (int u = 0; u < 100; u++)
    dst[u * 256 + v] = __expf(b2f(tile[u * 256 + v]) - mx) * inv;
}

extern "C" void kernel_launch(void* const* d_in, const int* in_sizes, int n_in,
                              void* d_out, int out_size, void* d_ws, size_t ws_size,
                              hipStream_t stream)
{
  (void)in_sizes; (void)n_in;
  const float* z     = (const float*)d_in[0];
  const float* Wzh   = (const float*)d_in[1];
  const float* bzh   = (const float*)d_in[2];
  const float* Wzc   = (const float*)d_in[3];
  const float* bzc   = (const float*)d_in[4];
  const float* g_bnzh= (const float*)d_in[5];
  const float* b_bnzh= (const float*)d_in[6];
  const float* g_bnzc= (const float*)d_in[7];
  const float* b_bnzc= (const float*)d_in[8];
  const float* Wih   = (const float*)d_in[9];
  const float* bih   = (const float*)d_in[10];
  const float* Whh   = (const float*)d_in[11];
  const float* bhh   = (const float*)d_in[12];
  const float* g_bn0 = (const float*)d_in[13];
  const float* b_bn0 = (const float*)d_in[14];
  const float* W1    = (const float*)d_in[15];
  const float* b1    = (const float*)d_in[16];
  const float* g_bn1 = (const float*)d_in[17];
  const float* b_bn1 = (const float*)d_in[18];
  const float* W2    = (const float*)d_in[19];
  const float* b2    = (const float*)d_in[20];
  const float* g_bn2 = (const float*)d_in[21];
  const float* b_bn2 = (const float*)d_in[22];
  const float* W3    = (const float*)d_in[23];
  const float* b3    = (const float*)d_in[24];
  const float* go    = (const float*)d_in[25];

  char* base = (char*)d_ws;
  size_t off = 0;
  auto alloc = [&](size_t bytes)->char*{
    char* p = base + off;
    off = (off + bytes + 255) & ~(size_t)255;
    return p;
  };
  const size_t MB = 1024 * 1024;

  unsigned short* ys = (unsigned short*)alloc(128 * MB);  // [b*1024+h][256] bf16
  unsigned short* o1 = (unsigned short*)alloc(64 * MB);   // [65536][512] bf16
  char* zone = alloc(32 * MB);                            // dead after LSTM; o2 overlays
  unsigned short* Wsum_p = (unsigned short*)(zone);            // 8 MB
  unsigned short* Whh_b  = (unsigned short*)(zone + 8 * MB);   // 8 MB
  float*          gates0 = (float*)(zone + 16 * MB);           // 4 MB
  // persistent-small region
  float* zh_raw = (float*)alloc(1 * MB);
  float* zc_raw = (float*)alloc(1 * MB);
  float* bias_sp = (float*)alloc(16384);
  float* bias0   = (float*)alloc(16384);
  unsigned short* zh_b  = (unsigned short*)alloc((size_t)256 * 1024 * 2);
  unsigned short* hbuf0 = (unsigned short*)alloc((size_t)256 * 1024 * 2);
  unsigned short* hbuf1 = (unsigned short*)alloc((size_t)256 * 1024 * 2);
  float* c_f    = (float*)alloc((size_t)256 * 1024 * 4);
  float* psum   = (float*)alloc(1 * MB);
  float* psq    = (float*)alloc(1 * MB);
  float* alpha0 = (float*)alloc(4096); float* beta0 = (float*)alloc(4096);
  float* alpha1 = (float*)alloc(4096); float* beta1 = (float*)alloc(4096);
  float* alpha2 = (float*)alloc(4096); float* beta2 = (float*)alloc(4096);
  unsigned short* W1b = (unsigned short*)alloc((size_t)512 * 1024 * 2);
  unsigned short* W2b = (unsigned short*)alloc((size_t)256 * 512 * 2);
  unsigned short* W3b = (unsigned short*)alloc((size_t)128 * 256 * 2);
  float* b1p = (float*)alloc(4096);
  float* b2p = (float*)alloc(4096);
  float* b3p = (float*)alloc(4096);
  unsigned int* bar = (unsigned int*)alloc(256);
  unsigned short* o2  = (unsigned short*)zone;  // 32 MB overlays dead zone
  unsigned short* o3p = o1;                     // 16 MB overlays dead o1

  if (off > ws_size){
    zerofill<<<(out_size + 255) / 256, 256, 0, stream>>>((float*)d_out, out_size);
    return;
  }

  zerofill<<<1, 256, 0, stream>>>((float*)bar, 64);
  prep_w<<<16384, 256, 0, stream>>>(Wih, Whh, bih, bhh, Wsum_p, Whh_b, bias_sp);
  prep_b0<<<4096, 256, 0, stream>>>(Wih, go, bih, bhh, bias0);
  zproj<<<1024, 256, 0, stream>>>(z, Wzh, bzh, Wzc, bzc, zh_raw, zc_raw);
  bn_init<<<1024, 256, 0, stream>>>(zh_raw, zc_raw, g_bnzh, b_bnzh, g_bnzc, b_bnzc, zh_b, c_f);

  // step 0: gates0 = zh @ Whh^T + bias0(go-term folded); then cell
  gemm_bt2<1024, 0, 0><<<dim3(32, 4), 256, 0, stream>>>(zh_b, Whh_b, bias0, gates0, 4096);
  lstm_cell0<<<1024, 256, 0, stream>>>(gates0, c_f, hbuf0, ys);

  // steps 1..255 in one persistent kernel
  lstm_persist<<<128, 512, 0, stream>>>(Wsum_p, bias_sp, hbuf0, hbuf1, c_f, ys, bar);

  stats1<1024><<<dim3(4, 256), 256, 0, stream>>>(ys, psum, psq);
  stats2<<<4, 256, 0, stream>>>(psum, psq, g_bn0, b_bn0, alpha0, beta0, 1024);
  foldk<1024><<<512, 256, 0, stream>>>(W1, b1, alpha0, beta0, W1b, b1p, 512);
  gemm_bt2<1024, 1, 1><<<dim3(4, 1024), 256, 0, stream>>>(ys, W1b, b1p, o1, 512);

  stats1<512><<<dim3(2, 256), 256, 0, stream>>>(o1, psum, psq);
  stats2<<<2, 256, 0, stream>>>(psum, psq, g_bn1, b_bn1, alpha1, beta1, 512);
  foldk<512><<<256, 256, 0, stream>>>(W2, b2, alpha1, beta1, W2b, b2p, 256);
  gemm_bt2<512, 1, 1><<<dim3(2, 1024), 256, 0, stream>>>(o1, W2b, b2p, o2, 256);

  stats1<256><<<dim3(1, 256), 256, 0, stream>>>(o2, psum, psq);
  stats2<<<1, 256, 0, stream>>>(psum, psq, g_bn2, b_bn2, alpha2, beta2, 256);
  foldk<256><<<128, 256, 0, stream>>>(W3, b3, alpha2, beta2, W3b, b3p, 100);
  gemm_bt2<256, 0, 1><<<dim3(1, 1024), 256, 0, stream>>>(o2, W3b, b3p, o3p, 128);

  softmax_k<<<256, 256, 0, stream>>>(o3p, (float*)d_out);
}

// Round 6
// 16168.010 us; speedup vs baseline: 1.1353x; 1.1353x over previous
//
#include <hip/hip_runtime.h>
#include <hip/hip_bf16.h>

typedef __attribute__((ext_vector_type(8))) short bf16x8;
typedef __attribute__((ext_vector_type(4))) float f32x4;

#define NBLK 128

__device__ inline unsigned short f2b(float x){
  union { float f; unsigned int u; } v; v.f = x;
  unsigned int u = v.u;
  return (unsigned short)((u + 0x7FFFu + ((u >> 16) & 1u)) >> 16);
}
__device__ inline float b2f(unsigned short h){
  union { unsigned int u; float f; } v; v.u = ((unsigned int)h) << 16; return v.f;
}
__device__ inline float sigm(float x){ return 1.f / (1.f + __expf(-x)); }
__device__ inline float tanh_f(float x){ float e2 = __expf(2.f * x); return 1.f - 2.f / (e2 + 1.f); }

__global__ __launch_bounds__(256) void zerofill(float* __restrict__ p, int n){
  int i = blockIdx.x * 256 + threadIdx.x;
  if (i < n) p[i] = 0.f;
}

// packed row for gate-row n = g*1024 + h:  blk = h>>3, local = (h&7)*4 + g
__device__ inline int packrow(int n){
  int g = n >> 10, h = n & 1023;
  return (h >> 3) * 32 + (h & 7) * 4 + g;
}

// ---- prep: Wsum as per-block LDS images (MFMA fragment order), Whh plain bf16, biases ----
__global__ __launch_bounds__(256) void prep_w(
    const float* __restrict__ Wih, const float* __restrict__ Whh,
    const float* __restrict__ bih, const float* __restrict__ bhh,
    unsigned short* __restrict__ Wsum_p, unsigned short* __restrict__ Whh_b,
    float* __restrict__ bias_sp)
{
  size_t idx = (size_t)blockIdx.x * 256 + threadIdx.x; // 4096*1024
  int n = (int)(idx >> 10), k = (int)(idx & 1023);
  int g = n >> 10, h = n & 1023;
  float wi = Wih[idx], wh = Whh[idx];
  int blk = h >> 3;
  int r  = ((h & 7) << 2) | g;         // local row 0..31
  int nt = r >> 4, lr2 = r & 15;
  int kb = k >> 5, lg2 = (k >> 3) & 3, e = k & 7;
  size_t dest = (size_t)blk * 32768 + (size_t)nt * 16384 + (size_t)kb * 512
              + (size_t)(lg2 * 16 + lr2) * 8 + e;
  Wsum_p[dest] = f2b(wi + wh);
  Whh_b[idx] = f2b(wh);
  if (idx < 4096) bias_sp[packrow((int)idx)] = bih[idx] + bhh[idx];
}

// bias0[n] (plain) = bih+bhh + sum_k W_ih[n,k]*go[0,k]
__global__ __launch_bounds__(256) void prep_b0(
    const float* __restrict__ Wih, const float* __restrict__ go,
    const float* __restrict__ bih, const float* __restrict__ bhh,
    float* __restrict__ bias0)
{
  __shared__ float red[4];
  int n = blockIdx.x, t = threadIdx.x;
  float acc = 0.f;
  for (int k = t; k < 1024; k += 256) acc += Wih[(size_t)n*1024 + k] * go[k];
  for (int off = 32; off > 0; off >>= 1) acc += __shfl_down(acc, off, 64);
  if ((t & 63) == 0) red[t >> 6] = acc;
  __syncthreads();
  if (t == 0) bias0[n] = bih[n] + bhh[n] + red[0] + red[1] + red[2] + red[3];
}

// ---- z projections (K=128, f32) ----
__global__ __launch_bounds__(256) void zproj(
    const float* __restrict__ z, const float* __restrict__ Wzh, const float* __restrict__ bzh,
    const float* __restrict__ Wzc, const float* __restrict__ bzc,
    float* __restrict__ zh_raw, float* __restrict__ zc_raw)
{
  int idx = blockIdx.x * 256 + threadIdx.x; // 256*1024
  int b = idx >> 10, c = idx & 1023;
  const float* zr = z + b * 128;
  const float* wh = Wzh + c * 128;
  const float* wc = Wzc + c * 128;
  float s1 = bzh[c], s2 = bzc[c];
  #pragma unroll 8
  for (int k = 0; k < 128; k++){ float zv = zr[k]; s1 += zv * wh[k]; s2 += zv * wc[k]; }
  zh_raw[idx] = s1; zc_raw[idx] = s2;
}

// ---- BN over batch: zh -> zh_b (bf16), zc -> c_f (f32) ----
__global__ __launch_bounds__(256) void bn_init(
    const float* __restrict__ zh_raw, const float* __restrict__ zc_raw,
    const float* __restrict__ g_h, const float* __restrict__ bt_h,
    const float* __restrict__ g_c, const float* __restrict__ bt_c,
    unsigned short* __restrict__ zh_b, float* __restrict__ c_f)
{
  __shared__ float red[4][4];
  int c = blockIdx.x, r = threadIdx.x;
  float v1 = zh_raw[r * 1024 + c];
  float v2 = zc_raw[r * 1024 + c];
  float s[4] = { v1, v1*v1, v2, v2*v2 };
  #pragma unroll
  for (int i = 0; i < 4; i++){
    float x = s[i];
    for (int off = 32; off > 0; off >>= 1) x += __shfl_down(x, off, 64);
    if ((r & 63) == 0) red[i][r >> 6] = x;
  }
  __syncthreads();
  float m1 = (red[0][0]+red[0][1]+red[0][2]+red[0][3]) * (1.f/256.f);
  float q1 = (red[1][0]+red[1][1]+red[1][2]+red[1][3]) * (1.f/256.f);
  float m2 = (red[2][0]+red[2][1]+red[2][2]+red[2][3]) * (1.f/256.f);
  float q2 = (red[3][0]+red[3][1]+red[3][2]+red[3][3]) * (1.f/256.f);
  float var1 = q1 - m1*m1; if (var1 < 0.f) var1 = 0.f;
  float var2 = q2 - m2*m2; if (var2 < 0.f) var2 = 0.f;
  float a1 = g_h[c] * rsqrtf(var1 + 1e-5f), be1 = bt_h[c] - m1*a1;
  float a2 = g_c[c] * rsqrtf(var2 + 1e-5f), be2 = bt_c[c] - m2*a2;
  zh_b[r * 1024 + c] = f2b(v1*a1 + be1);
  c_f[r * 1024 + c] = v2*a2 + be2;
}

// ---- MLP / step0 GEMM: out[M][N] = A[M][K] @ B[N][K]^T + bias; 64x128 tile ----
template<int K, int ACT, int OBF16>
__global__ __launch_bounds__(256) void gemm_bt2(
    const unsigned short* __restrict__ A, const unsigned short* __restrict__ B,
    const float* __restrict__ bias, void* __restrict__ outp, int N)
{
  const int tid = threadIdx.x;
  const int w = tid >> 6, l = tid & 63;
  const int lr = l & 15, lg = l >> 4;
  const int m0 = blockIdx.y * 64 + (w >> 1) * 32;
  const int n0 = blockIdx.x * 128 + (w & 1) * 64;
  f32x4 acc[2][4];
  #pragma unroll
  for (int i = 0; i < 2; i++)
    #pragma unroll
    for (int j = 0; j < 4; j++) acc[i][j] = (f32x4){0.f,0.f,0.f,0.f};

  const unsigned short* pa0 = A + (size_t)(m0 + lr) * K + lg * 8;
  const unsigned short* pa1 = pa0 + (size_t)16 * K;
  const unsigned short* pb0 = B + (size_t)(n0 + lr) * K + lg * 8;

  for (int kb = 0; kb < K; kb += 32){
    bf16x8 a0 = *(const bf16x8*)(pa0 + kb);
    bf16x8 a1 = *(const bf16x8*)(pa1 + kb);
    bf16x8 b0 = *(const bf16x8*)(pb0 + kb);
    bf16x8 b1 = *(const bf16x8*)(pb0 + (size_t)16 * K + kb);
    bf16x8 b2 = *(const bf16x8*)(pb0 + (size_t)32 * K + kb);
    bf16x8 b3 = *(const bf16x8*)(pb0 + (size_t)48 * K + kb);
    acc[0][0] = __builtin_amdgcn_mfma_f32_16x16x32_bf16(a0, b0, acc[0][0], 0, 0, 0);
    acc[0][1] = __builtin_amdgcn_mfma_f32_16x16x32_bf16(a0, b1, acc[0][1], 0, 0, 0);
    acc[0][2] = __builtin_amdgcn_mfma_f32_16x16x32_bf16(a0, b2, acc[0][2], 0, 0, 0);
    acc[0][3] = __builtin_amdgcn_mfma_f32_16x16x32_bf16(a0, b3, acc[0][3], 0, 0, 0);
    acc[1][0] = __builtin_amdgcn_mfma_f32_16x16x32_bf16(a1, b0, acc[1][0], 0, 0, 0);
    acc[1][1] = __builtin_amdgcn_mfma_f32_16x16x32_bf16(a1, b1, acc[1][1], 0, 0, 0);
    acc[1][2] = __builtin_amdgcn_mfma_f32_16x16x32_bf16(a1, b2, acc[1][2], 0, 0, 0);
    acc[1][3] = __builtin_amdgcn_mfma_f32_16x16x32_bf16(a1, b3, acc[1][3], 0, 0, 0);
  }

  #pragma unroll
  for (int mi = 0; mi < 2; mi++)
    #pragma unroll
    for (int ni = 0; ni < 4; ni++){
      int col = n0 + ni * 16 + lr;
      float bs = bias[col];
      #pragma unroll
      for (int j = 0; j < 4; j++){
        int row = m0 + mi * 16 + lg * 4 + j;
        float v = acc[mi][ni][j] + bs;
        if (ACT) v = v > 0.f ? v : 0.01f * v;
        if (OBF16) ((unsigned short*)outp)[(size_t)row * N + col] = f2b(v);
        else       ((float*)outp)[(size_t)row * N + col] = v;
      }
    }
}

// ---- step-0 cell: gates0 -> c, h(0) into hbuf0 ----
__global__ __launch_bounds__(256) void lstm_cell0(
    const float* __restrict__ gates, float* __restrict__ c,
    unsigned short* __restrict__ hbuf0)
{
  int idx = blockIdx.x * 256 + threadIdx.x; // 256*1024
  int b = idx >> 10, h = idx & 1023;
  const float* g = gates + (size_t)b * 4096;
  float ig = g[h], fg = g[1024 + h], gg = g[2048 + h], og = g[3072 + h];
  float co = c[idx];
  float c2 = sigm(fg) * co + sigm(ig) * tanh_f(gg);
  float h2 = sigm(og) * tanh_f(c2);
  c[idx] = c2;
  hbuf0[idx] = f2b(h2);
}

// ---- persistent LSTM: steps 1..255, grid barrier (RMW poll), W in LDS, ys via LDS chunk ----
// 128 blocks x 512 threads. Block blk owns h-cols [blk*8, blk*8+8) = 32 packed gate-rows.
__global__ __launch_bounds__(512, 1) void lstm_persist(
    const unsigned short* __restrict__ Wp, const float* __restrict__ bias_sp,
    unsigned short* __restrict__ hbuf0, unsigned short* __restrict__ hbuf1,
    const float* __restrict__ c_init, unsigned short* __restrict__ ys,
    unsigned int* __restrict__ cnt)
{
  __shared__ unsigned short Wl[32768];        // 64 KB: fragment-order image, conflict-free
  __shared__ unsigned short chunk[2048][20];  // 80 KB: [b*8+hl][t&15] (+pad), 16-step ys chunk
  const int tid = threadIdx.x;
  const int blk = blockIdx.x;
  const int w = tid >> 6, l = tid & 63;
  const int lr = l & 15, lg = l >> 4;

  // stage W image: contiguous copy (layout prebaked by prep_w)
  {
    const bf16x8* src = (const bf16x8*)(Wp + (size_t)blk * 32768);
    bf16x8* dst = (bf16x8*)Wl;
    for (int i = tid; i < 4096; i += 512) dst[i] = src[i];
  }
  // preload t=0 h into chunk slot 0 (written by lstm_cell0 into hbuf0)
  for (int i = tid; i < 2048; i += 512){
    int b = i >> 3, hl = i & 7;
    chunk[i][0] = hbuf0[(size_t)b * 1024 + blk * 8 + hl];
  }

  const int hw0 = lr >> 2;
  float bb[2];
  bb[0] = bias_sp[blk * 32 + lr];
  bb[1] = bias_sp[blk * 32 + 16 + lr];

  float creg[2][2][4];
  #pragma unroll
  for (int mi = 0; mi < 2; mi++)
    #pragma unroll
    for (int ni = 0; ni < 2; ni++)
      #pragma unroll
      for (int j = 0; j < 4; j++){
        int row = w * 32 + mi * 16 + lg * 4 + j;
        int h = blk * 8 + ni * 4 + hw0;
        creg[mi][ni][j] = c_init[(size_t)row * 1024 + h];
      }

  __syncthreads();

  const char* lwb = (const char*)Wl + l * 16;

  #pragma unroll 1
  for (int t = 1; t < 256; t++){
    const unsigned short* hin  = (t & 1) ? hbuf0 : hbuf1;
    unsigned short*       hout = (t & 1) ? hbuf1 : hbuf0;

    f32x4 acc[2][2];
    #pragma unroll
    for (int i = 0; i < 2; i++)
      #pragma unroll
      for (int j = 0; j < 2; j++) acc[i][j] = (f32x4){0.f,0.f,0.f,0.f};

    const unsigned short* pa0 = hin + (size_t)(w * 32 + lr) * 1024 + lg * 8;
    const unsigned short* pa1 = pa0 + 16 * 1024;

    #pragma unroll 8
    for (int kb = 0; kb < 32; kb++){
      bf16x8 a0 = *(const bf16x8*)(pa0 + kb * 32);
      bf16x8 a1 = *(const bf16x8*)(pa1 + kb * 32);
      bf16x8 b0 = *(const bf16x8*)(lwb + kb * 1024);
      bf16x8 b1 = *(const bf16x8*)(lwb + 32768 + kb * 1024);
      acc[0][0] = __builtin_amdgcn_mfma_f32_16x16x32_bf16(a0, b0, acc[0][0], 0, 0, 0);
      acc[0][1] = __builtin_amdgcn_mfma_f32_16x16x32_bf16(a0, b1, acc[0][1], 0, 0, 0);
      acc[1][0] = __builtin_amdgcn_mfma_f32_16x16x32_bf16(a1, b0, acc[1][0], 0, 0, 0);
      acc[1][1] = __builtin_amdgcn_mfma_f32_16x16x32_bf16(a1, b1, acc[1][1], 0, 0, 0);
    }

    // cell epilogue: reunite 4 gates across the 4 gate-lanes (lr&3)
    #pragma unroll
    for (int mi = 0; mi < 2; mi++)
      #pragma unroll
      for (int ni = 0; ni < 2; ni++)
        #pragma unroll
        for (int j = 0; j < 4; j++){
          float v = acc[mi][ni][j] + bb[ni];
          float va = v;
          float vb = __shfl_xor(v, 1);
          float vc = __shfl_xor(v, 2);
          float vd = __shfl_xor(vb, 2);
          bool s1 = (lr & 1), s2 = (lr & 2);
          float P1 = s2 ? vc : va, P2 = s2 ? vd : vb;
          float Q1 = s2 ? va : vc, Q2 = s2 ? vb : vd;
          float gi  = s1 ? P2 : P1;
          float gf  = s1 ? P1 : P2;
          float gg  = s1 ? Q2 : Q1;
          float go_ = s1 ? Q1 : Q2;
          float c2 = sigm(gf) * creg[mi][ni][j] + sigm(gi) * tanh_f(gg);
          float h2 = sigm(go_) * tanh_f(c2);
          creg[mi][ni][j] = c2;
          unsigned short hb = f2b(h2);
          int row = w * 32 + mi * 16 + lg * 4 + j;
          int hl = ni * 4 + hw0;
          if ((lr & 3) == 0) chunk[row * 8 + hl][t & 15] = hb;                 // LDS, block-local
          if ((lr & 3) == 1) hout[(size_t)row * 1024 + blk * 8 + hl] = hb;     // 0.5MB/step global
        }

    // dump 16-step chunk to ys (contiguous 32B per row)
    if ((t & 15) == 15){
      __syncthreads();
      int t0 = t - 15;
      for (int r = tid; r < 2048; r += 512){
        int b = r >> 3, hl = r & 7;
        uint2 p0 = *(const uint2*)&chunk[r][0];
        uint2 p1 = *(const uint2*)&chunk[r][4];
        uint2 p2 = *(const uint2*)&chunk[r][8];
        uint2 p3 = *(const uint2*)&chunk[r][12];
        size_t o = ((size_t)b * 1024 + blk * 8 + hl) * 256 + t0;
        *(uint4*)&ys[o]     = (uint4){p0.x, p0.y, p1.x, p1.y};
        *(uint4*)&ys[o + 8] = (uint4){p2.x, p2.y, p3.x, p3.y};
      }
    }

    if (t < 255){
      __threadfence();      // release: wbL2 (only ~0.5MB dirty now)
      __syncthreads();
      if (tid == 0){
        __hip_atomic_fetch_add(&cnt[t], 1u, __ATOMIC_ACQ_REL, __HIP_MEMORY_SCOPE_AGENT);
        int spin = 0;
        while (__hip_atomic_fetch_add(&cnt[t], 0u, __ATOMIC_RELAXED,
                                      __HIP_MEMORY_SCOPE_AGENT) < (unsigned)NBLK
               && spin < (1 << 20)){
          __builtin_amdgcn_s_sleep(8);
          ++spin;
        }
      }
      __syncthreads();
      __threadfence();      // acquire: invalidate stale hin lines
    }
  }
}

// ---- column stats (sum, sumsq), stage 1 ----
template<int C>
__global__ __launch_bounds__(256) void stats1(
    const unsigned short* __restrict__ X, float* __restrict__ psum, float* __restrict__ psq)
{
  int col = blockIdx.x * 256 + threadIdx.x;
  int r0 = blockIdx.y * 256;
  float s = 0.f, q = 0.f;
  for (int r = r0; r < r0 + 256; r++){
    float v = b2f(X[(size_t)r * C + col]);
    s += v; q += v * v;
  }
  psum[(size_t)blockIdx.y * C + col] = s;
  psq [(size_t)blockIdx.y * C + col] = q;
}

__global__ __launch_bounds__(256) void stats2(
    const float* __restrict__ psum, const float* __restrict__ psq,
    const float* __restrict__ g, const float* __restrict__ b,
    float* __restrict__ alpha, float* __restrict__ beta, int C)
{
  int c = blockIdx.x * 256 + threadIdx.x;
  if (c >= C) return;
  float s = 0.f, q = 0.f;
  for (int i = 0; i < 256; i++){ s += psum[(size_t)i * C + c]; q += psq[(size_t)i * C + c]; }
  float m = s * (1.f / 65536.f);
  float var = q * (1.f / 65536.f) - m * m; if (var < 0.f) var = 0.f;
  float a = g[c] * rsqrtf(var + 1e-5f);
  alpha[c] = a; beta[c] = b[c] - m * a;
}

// ---- fold BN into weights ----
template<int K>
__global__ __launch_bounds__(256) void foldk(
    const float* __restrict__ W, const float* __restrict__ bias,
    const float* __restrict__ alpha, const float* __restrict__ beta,
    unsigned short* __restrict__ Wb, float* __restrict__ bp, int rows)
{
  __shared__ float red[4];
  int o = blockIdx.x, t = threadIdx.x;
  float acc = 0.f;
  if (o < rows){
    for (int j = t; j < K; j += 256){
      float wv = W[(size_t)o * K + j];
      acc += beta[j] * wv;
      Wb[(size_t)o * K + j] = f2b(wv * alpha[j]);
    }
  } else {
    for (int j = t; j < K; j += 256) Wb[(size_t)o * K + j] = 0;
  }
  for (int off = 32; off > 0; off >>= 1) acc += __shfl_down(acc, off, 64);
  if ((t & 63) == 0) red[t >> 6] = acc;
  __syncthreads();
  if (t == 0) bp[o] = (o < rows ? bias[o] : 0.f) + red[0] + red[1] + red[2] + red[3];
}

// ---- final softmax with raw-reshape index mixing ----
__global__ __launch_bounds__(256) void softmax_k(
    const unsigned short* __restrict__ o3p, float* __restrict__ out)
{
  __shared__ unsigned short tile[25600];
  int b = blockIdx.x, t = threadIdx.x;
  const unsigned short* src = o3p + (size_t)b * 256 * 128;
  for (int i = t; i < 25600; i += 256){
    int rr = i / 100, nc = i - rr * 100;
    tile[i] = src[rr * 128 + nc];
  }
  __syncthreads();
  int v = t;
  float mx = -1e30f;
  for (int u = 0; u < 100; u++) mx = fmaxf(mx, b2f(tile[u * 256 + v]));
  float s = 0.f;
  for (int u = 0; u < 100; u++) s += __expf(b2f(tile[u * 256 + v]) - mx);
  float inv = 1.f / s;
  float* dst = out + (size_t)b * 25600;
  for (int u = 0; u < 100; u++)
    dst[u * 256 + v] = __expf(b2f(tile[u * 256 + v]) - mx) * inv;
}

extern "C" void kernel_launch(void* const* d_in, const int* in_sizes, int n_in,
                              void* d_out, int out_size, void* d_ws, size_t ws_size,
                              hipStream_t stream)
{
  (void)in_sizes; (void)n_in;
  const float* z     = (const float*)d_in[0];
  const float* Wzh   = (const float*)d_in[1];
  const float* bzh   = (const float*)d_in[2];
  const float* Wzc   = (const float*)d_in[3];
  const float* bzc   = (const float*)d_in[4];
  const float* g_bnzh= (const float*)d_in[5];
  const float* b_bnzh= (const float*)d_in[6];
  const float* g_bnzc= (const float*)d_in[7];
  const float* b_bnzc= (const float*)d_in[8];
  const float* Wih   = (const float*)d_in[9];
  const float* bih   = (const float*)d_in[10];
  const float* Whh   = (const float*)d_in[11];
  const float* bhh   = (const float*)d_in[12];
  const float* g_bn0 = (const float*)d_in[13];
  const float* b_bn0 = (const float*)d_in[14];
  const float* W1    = (const float*)d_in[15];
  const float* b1    = (const float*)d_in[16];
  const float* g_bn1 = (const float*)d_in[17];
  const float* b_bn1 = (const float*)d_in[18];
  const float* W2    = (const float*)d_in[19];
  const float* b2    = (const float*)d_in[20];
  const float* g_bn2 = (const float*)d_in[21];
  const float* b_bn2 = (const float*)d_in[22];
  const float* W3    = (const float*)d_in[23];
  const float* b3    = (const float*)d_in[24];
  const float* go    = (const float*)d_in[25];

  char* base = (char*)d_ws;
  size_t off = 0;
  auto alloc = [&](size_t bytes)->char*{
    char* p = base + off;
    off = (off + bytes + 255) & ~(size_t)255;
    return p;
  };
  const size_t MB = 1024 * 1024;

  unsigned short* ys = (unsigned short*)alloc(128 * MB);  // [b*1024+h][256] bf16
  unsigned short* o1 = (unsigned short*)alloc(64 * MB);   // [65536][512] bf16
  char* zone = alloc(32 * MB);                            // dead after LSTM; o2 overlays
  unsigned short* Wsum_p = (unsigned short*)(zone);            // 8 MB
  unsigned short* Whh_b  = (unsigned short*)(zone + 8 * MB);   // 8 MB
  float*          gates0 = (float*)(zone + 16 * MB);           // 4 MB
  // persistent-small region
  float* zh_raw = (float*)alloc(1 * MB);
  float* zc_raw = (float*)alloc(1 * MB);
  float* bias_sp = (float*)alloc(16384);
  float* bias0   = (float*)alloc(16384);
  unsigned short* zh_b  = (unsigned short*)alloc((size_t)256 * 1024 * 2);
  unsigned short* hbuf0 = (unsigned short*)alloc((size_t)256 * 1024 * 2);
  unsigned short* hbuf1 = (unsigned short*)alloc((size_t)256 * 1024 * 2);
  float* c_f    = (float*)alloc((size_t)256 * 1024 * 4);
  float* psum   = (float*)alloc(1 * MB);
  float* psq    = (float*)alloc(1 * MB);
  float* alpha0 = (float*)alloc(4096); float* beta0 = (float*)alloc(4096);
  float* alpha1 = (float*)alloc(4096); float* beta1 = (float*)alloc(4096);
  float* alpha2 = (float*)alloc(4096); float* beta2 = (float*)alloc(4096);
  unsigned short* W1b = (unsigned short*)alloc((size_t)512 * 1024 * 2);
  unsigned short* W2b = (unsigned short*)alloc((size_t)256 * 512 * 2);
  unsigned short* W3b = (unsigned short*)alloc((size_t)128 * 256 * 2);
  float* b1p = (float*)alloc(4096);
  float* b2p = (float*)alloc(4096);
  float* b3p = (float*)alloc(4096);
  unsigned int* cnt = (unsigned int*)alloc(4096);  // cnt[256]
  unsigned short* o2  = (unsigned short*)zone;  // 32 MB overlays dead zone
  unsigned short* o3p = o1;                     // 16 MB overlays dead o1

  if (off > ws_size){
    zerofill<<<(out_size + 255) / 256, 256, 0, stream>>>((float*)d_out, out_size);
    return;
  }

  zerofill<<<1, 256, 0, stream>>>((float*)cnt, 256);
  prep_w<<<16384, 256, 0, stream>>>(Wih, Whh, bih, bhh, Wsum_p, Whh_b, bias_sp);
  prep_b0<<<4096, 256, 0, stream>>>(Wih, go, bih, bhh, bias0);
  zproj<<<1024, 256, 0, stream>>>(z, Wzh, bzh, Wzc, bzc, zh_raw, zc_raw);
  bn_init<<<1024, 256, 0, stream>>>(zh_raw, zc_raw, g_bnzh, b_bnzh, g_bnzc, b_bnzc, zh_b, c_f);

  // step 0: gates0 = zh @ Whh^T + bias0(go-term folded); then cell
  gemm_bt2<1024, 0, 0><<<dim3(32, 4), 256, 0, stream>>>(zh_b, Whh_b, bias0, gates0, 4096);
  lstm_cell0<<<1024, 256, 0, stream>>>(gates0, c_f, hbuf0);

  // steps 1..255 in one persistent kernel
  lstm_persist<<<NBLK, 512, 0, stream>>>(Wsum_p, bias_sp, hbuf0, hbuf1, c_f, ys, cnt);

  stats1<1024><<<dim3(4, 256), 256, 0, stream>>>(ys, psum, psq);
  stats2<<<4, 256, 0, stream>>>(psum, psq, g_bn0, b_bn0, alpha0, beta0, 1024);
  foldk<1024><<<512, 256, 0, stream>>>(W1, b1, alpha0, beta0, W1b, b1p, 512);
  gemm_bt2<1024, 1, 1><<<dim3(4, 1024), 256, 0, stream>>>(ys, W1b, b1p, o1, 512);

  stats1<512><<<dim3(2, 256), 256, 0, stream>>>(o1, psum, psq);
  stats2<<<2, 256, 0, stream>>>(psum, psq, g_bn1, b_bn1, alpha1, beta1, 512);
  foldk<512><<<256, 256, 0, stream>>>(W2, b2, alpha1, beta1, W2b, b2p, 256);
  gemm_bt2<512, 1, 1><<<dim3(2, 1024), 256, 0, stream>>>(o1, W2b, b2p, o2, 256);

  stats1<256><<<dim3(1, 256), 256, 0, stream>>>(o2, psum, psq);
  stats2<<<1, 256, 0, stream>>>(psum, psq, g_bn2, b_bn2, alpha2, beta2, 256);
  foldk<256><<<128, 256, 0, stream>>>(W3, b3, alpha2, beta2, W3b, b3p, 100);
  gemm_bt2<256, 0, 1><<<dim3(1, 1024), 256, 0, stream>>>(o2, W3b, b3p, o3p, 128);

  softmax_k<<<256, 256, 0, stream>>>(o3p, (float*)d_out);
}

// Round 7
// 12155.259 us; speedup vs baseline: 1.5102x; 1.3301x over previous
//
#include <hip/hip_runtime.h>
#include <hip/hip_bf16.h>

typedef __attribute__((ext_vector_type(8))) short bf16x8;
typedef __attribute__((ext_vector_type(4))) float f32x4;

#define NBLK 128

__device__ inline unsigned short f2b(float x){
  union { float f; unsigned int u; } v; v.f = x;
  unsigned int u = v.u;
  return (unsigned short)((u + 0x7FFFu + ((u >> 16) & 1u)) >> 16);
}
__device__ inline float b2f(unsigned short h){
  union { unsigned int u; float f; } v; v.u = ((unsigned int)h) << 16; return v.f;
}
__device__ inline float sigm(float x){ return 1.f / (1.f + __expf(-x)); }
__device__ inline float tanh_f(float x){ float e2 = __expf(2.f * x); return 1.f - 2.f / (e2 + 1.f); }

__global__ __launch_bounds__(256) void zerofill(float* __restrict__ p, int n){
  int i = blockIdx.x * 256 + threadIdx.x;
  if (i < n) p[i] = 0.f;
}

// packed row for gate-row n = g*1024 + h:  blk = h>>3, local = (h&7)*4 + g
__device__ inline int packrow(int n){
  int g = n >> 10, h = n & 1023;
  return (h >> 3) * 32 + (h & 7) * 4 + g;
}

// ---- prep: Wsum as per-block LDS images (MFMA fragment order), Whh plain bf16, biases ----
__global__ __launch_bounds__(256) void prep_w(
    const float* __restrict__ Wih, const float* __restrict__ Whh,
    const float* __restrict__ bih, const float* __restrict__ bhh,
    unsigned short* __restrict__ Wsum_p, unsigned short* __restrict__ Whh_b,
    float* __restrict__ bias_sp)
{
  size_t idx = (size_t)blockIdx.x * 256 + threadIdx.x; // 4096*1024
  int n = (int)(idx >> 10), k = (int)(idx & 1023);
  int g = n >> 10, h = n & 1023;
  float wi = Wih[idx], wh = Whh[idx];
  int blk = h >> 3;
  int r  = ((h & 7) << 2) | g;         // local row 0..31
  int nt = r >> 4, lr2 = r & 15;
  int kb = k >> 5, lg2 = (k >> 3) & 3, e = k & 7;
  size_t dest = (size_t)blk * 32768 + (size_t)nt * 16384 + (size_t)kb * 512
              + (size_t)(lg2 * 16 + lr2) * 8 + e;
  Wsum_p[dest] = f2b(wi + wh);
  Whh_b[idx] = f2b(wh);
  if (idx < 4096) bias_sp[packrow((int)idx)] = bih[idx] + bhh[idx];
}

// bias0[n] (plain) = bih+bhh + sum_k W_ih[n,k]*go[0,k]
__global__ __launch_bounds__(256) void prep_b0(
    const float* __restrict__ Wih, const float* __restrict__ go,
    const float* __restrict__ bih, const float* __restrict__ bhh,
    float* __restrict__ bias0)
{
  __shared__ float red[4];
  int n = blockIdx.x, t = threadIdx.x;
  float acc = 0.f;
  for (int k = t; k < 1024; k += 256) acc += Wih[(size_t)n*1024 + k] * go[k];
  for (int off = 32; off > 0; off >>= 1) acc += __shfl_down(acc, off, 64);
  if ((t & 63) == 0) red[t >> 6] = acc;
  __syncthreads();
  if (t == 0) bias0[n] = bih[n] + bhh[n] + red[0] + red[1] + red[2] + red[3];
}

// ---- z projections (K=128, f32) ----
__global__ __launch_bounds__(256) void zproj(
    const float* __restrict__ z, const float* __restrict__ Wzh, const float* __restrict__ bzh,
    const float* __restrict__ Wzc, const float* __restrict__ bzc,
    float* __restrict__ zh_raw, float* __restrict__ zc_raw)
{
  int idx = blockIdx.x * 256 + threadIdx.x; // 256*1024
  int b = idx >> 10, c = idx & 1023;
  const float* zr = z + b * 128;
  const float* wh = Wzh + c * 128;
  const float* wc = Wzc + c * 128;
  float s1 = bzh[c], s2 = bzc[c];
  #pragma unroll 8
  for (int k = 0; k < 128; k++){ float zv = zr[k]; s1 += zv * wh[k]; s2 += zv * wc[k]; }
  zh_raw[idx] = s1; zc_raw[idx] = s2;
}

// ---- BN over batch: zh -> zh_b (bf16), zc -> c_f (f32) ----
__global__ __launch_bounds__(256) void bn_init(
    const float* __restrict__ zh_raw, const float* __restrict__ zc_raw,
    const float* __restrict__ g_h, const float* __restrict__ bt_h,
    const float* __restrict__ g_c, const float* __restrict__ bt_c,
    unsigned short* __restrict__ zh_b, float* __restrict__ c_f)
{
  __shared__ float red[4][4];
  int c = blockIdx.x, r = threadIdx.x;
  float v1 = zh_raw[r * 1024 + c];
  float v2 = zc_raw[r * 1024 + c];
  float s[4] = { v1, v1*v1, v2, v2*v2 };
  #pragma unroll
  for (int i = 0; i < 4; i++){
    float x = s[i];
    for (int off = 32; off > 0; off >>= 1) x += __shfl_down(x, off, 64);
    if ((r & 63) == 0) red[i][r >> 6] = x;
  }
  __syncthreads();
  float m1 = (red[0][0]+red[0][1]+red[0][2]+red[0][3]) * (1.f/256.f);
  float q1 = (red[1][0]+red[1][1]+red[1][2]+red[1][3]) * (1.f/256.f);
  float m2 = (red[2][0]+red[2][1]+red[2][2]+red[2][3]) * (1.f/256.f);
  float q2 = (red[3][0]+red[3][1]+red[3][2]+red[3][3]) * (1.f/256.f);
  float var1 = q1 - m1*m1; if (var1 < 0.f) var1 = 0.f;
  float var2 = q2 - m2*m2; if (var2 < 0.f) var2 = 0.f;
  float a1 = g_h[c] * rsqrtf(var1 + 1e-5f), be1 = bt_h[c] - m1*a1;
  float a2 = g_c[c] * rsqrtf(var2 + 1e-5f), be2 = bt_c[c] - m2*a2;
  zh_b[r * 1024 + c] = f2b(v1*a1 + be1);
  c_f[r * 1024 + c] = v2*a2 + be2;
}

// ---- MLP / step0 GEMM: out[M][N] = A[M][K] @ B[N][K]^T + bias; 64x128 tile ----
template<int K, int ACT, int OBF16>
__global__ __launch_bounds__(256) void gemm_bt2(
    const unsigned short* __restrict__ A, const unsigned short* __restrict__ B,
    const float* __restrict__ bias, void* __restrict__ outp, int N)
{
  const int tid = threadIdx.x;
  const int w = tid >> 6, l = tid & 63;
  const int lr = l & 15, lg = l >> 4;
  const int m0 = blockIdx.y * 64 + (w >> 1) * 32;
  const int n0 = blockIdx.x * 128 + (w & 1) * 64;
  f32x4 acc[2][4];
  #pragma unroll
  for (int i = 0; i < 2; i++)
    #pragma unroll
    for (int j = 0; j < 4; j++) acc[i][j] = (f32x4){0.f,0.f,0.f,0.f};

  const unsigned short* pa0 = A + (size_t)(m0 + lr) * K + lg * 8;
  const unsigned short* pa1 = pa0 + (size_t)16 * K;
  const unsigned short* pb0 = B + (size_t)(n0 + lr) * K + lg * 8;

  for (int kb = 0; kb < K; kb += 32){
    bf16x8 a0 = *(const bf16x8*)(pa0 + kb);
    bf16x8 a1 = *(const bf16x8*)(pa1 + kb);
    bf16x8 b0 = *(const bf16x8*)(pb0 + kb);
    bf16x8 b1 = *(const bf16x8*)(pb0 + (size_t)16 * K + kb);
    bf16x8 b2 = *(const bf16x8*)(pb0 + (size_t)32 * K + kb);
    bf16x8 b3 = *(const bf16x8*)(pb0 + (size_t)48 * K + kb);
    acc[0][0] = __builtin_amdgcn_mfma_f32_16x16x32_bf16(a0, b0, acc[0][0], 0, 0, 0);
    acc[0][1] = __builtin_amdgcn_mfma_f32_16x16x32_bf16(a0, b1, acc[0][1], 0, 0, 0);
    acc[0][2] = __builtin_amdgcn_mfma_f32_16x16x32_bf16(a0, b2, acc[0][2], 0, 0, 0);
    acc[0][3] = __builtin_amdgcn_mfma_f32_16x16x32_bf16(a0, b3, acc[0][3], 0, 0, 0);
    acc[1][0] = __builtin_amdgcn_mfma_f32_16x16x32_bf16(a1, b0, acc[1][0], 0, 0, 0);
    acc[1][1] = __builtin_amdgcn_mfma_f32_16x16x32_bf16(a1, b1, acc[1][1], 0, 0, 0);
    acc[1][2] = __builtin_amdgcn_mfma_f32_16x16x32_bf16(a1, b2, acc[1][2], 0, 0, 0);
    acc[1][3] = __builtin_amdgcn_mfma_f32_16x16x32_bf16(a1, b3, acc[1][3], 0, 0, 0);
  }

  #pragma unroll
  for (int mi = 0; mi < 2; mi++)
    #pragma unroll
    for (int ni = 0; ni < 4; ni++){
      int col = n0 + ni * 16 + lr;
      float bs = bias[col];
      #pragma unroll
      for (int j = 0; j < 4; j++){
        int row = m0 + mi * 16 + lg * 4 + j;
        float v = acc[mi][ni][j] + bs;
        if (ACT) v = v > 0.f ? v : 0.01f * v;
        if (OBF16) ((unsigned short*)outp)[(size_t)row * N + col] = f2b(v);
        else       ((float*)outp)[(size_t)row * N + col] = v;
      }
    }
}

// ---- step-0 cell: gates0 -> c, h(0) into hbuf0 ----
__global__ __launch_bounds__(256) void lstm_cell0(
    const float* __restrict__ gates, float* __restrict__ c,
    unsigned short* __restrict__ hbuf0)
{
  int idx = blockIdx.x * 256 + threadIdx.x; // 256*1024
  int b = idx >> 10, h = idx & 1023;
  const float* g = gates + (size_t)b * 4096;
  float ig = g[h], fg = g[1024 + h], gg = g[2048 + h], og = g[3072 + h];
  float co = c[idx];
  float c2 = sigm(fg) * co + sigm(ig) * tanh_f(gg);
  float h2 = sigm(og) * tanh_f(c2);
  c[idx] = c2;
  hbuf0[idx] = f2b(h2);
}

// ---- persistent LSTM: steps 1..255, distributed-flag grid barrier, W in LDS ----
// 128 blocks x 512 threads. Block blk owns h-cols [blk*8, blk*8+8) = 32 packed gate-rows.
__global__ __launch_bounds__(512, 1) void lstm_persist(
    const unsigned short* __restrict__ Wp, const float* __restrict__ bias_sp,
    unsigned short* __restrict__ hbuf0, unsigned short* __restrict__ hbuf1,
    const float* __restrict__ c_init, unsigned short* __restrict__ ys,
    unsigned int* __restrict__ cnt, unsigned int* __restrict__ flagv)
{
  __shared__ unsigned short Wl[32768];        // 64 KB: fragment-order image, conflict-free
  __shared__ unsigned short chunk[2048][20];  // 80 KB: [b*8+hl][t&15] (+pad), 16-step ys chunk
  const int tid = threadIdx.x;
  const int blk = blockIdx.x;
  const int w = tid >> 6, l = tid & 63;
  const int lr = l & 15, lg = l >> 4;

  // stage W image: contiguous copy (layout prebaked by prep_w)
  {
    const bf16x8* src = (const bf16x8*)(Wp + (size_t)blk * 32768);
    bf16x8* dst = (bf16x8*)Wl;
    for (int i = tid; i < 4096; i += 512) dst[i] = src[i];
  }
  // preload t=0 h into chunk slot 0 (written by lstm_cell0 into hbuf0)
  for (int i = tid; i < 2048; i += 512){
    int b = i >> 3, hl = i & 7;
    chunk[i][0] = hbuf0[(size_t)b * 1024 + blk * 8 + hl];
  }

  const int hw0 = lr >> 2;
  float bb[2];
  bb[0] = bias_sp[blk * 32 + lr];
  bb[1] = bias_sp[blk * 32 + 16 + lr];

  float creg[2][2][4];
  #pragma unroll
  for (int mi = 0; mi < 2; mi++)
    #pragma unroll
    for (int ni = 0; ni < 2; ni++)
      #pragma unroll
      for (int j = 0; j < 4; j++){
        int row = w * 32 + mi * 16 + lg * 4 + j;
        int h = blk * 8 + ni * 4 + hw0;
        creg[mi][ni][j] = c_init[(size_t)row * 1024 + h];
      }

  __syncthreads();

  const char* lwb = (const char*)Wl + l * 16;

  #pragma unroll 1
  for (int t = 1; t < 256; t++){
    const unsigned short* hin  = (t & 1) ? hbuf0 : hbuf1;
    unsigned short*       hout = (t & 1) ? hbuf1 : hbuf0;

    f32x4 acc[2][2];
    #pragma unroll
    for (int i = 0; i < 2; i++)
      #pragma unroll
      for (int j = 0; j < 2; j++) acc[i][j] = (f32x4){0.f,0.f,0.f,0.f};

    const unsigned short* pa0 = hin + (size_t)(w * 32 + lr) * 1024 + lg * 8;
    const unsigned short* pa1 = pa0 + 16 * 1024;

    #pragma unroll 8
    for (int kb = 0; kb < 32; kb++){
      bf16x8 a0 = *(const bf16x8*)(pa0 + kb * 32);
      bf16x8 a1 = *(const bf16x8*)(pa1 + kb * 32);
      bf16x8 b0 = *(const bf16x8*)(lwb + kb * 1024);
      bf16x8 b1 = *(const bf16x8*)(lwb + 32768 + kb * 1024);
      acc[0][0] = __builtin_amdgcn_mfma_f32_16x16x32_bf16(a0, b0, acc[0][0], 0, 0, 0);
      acc[0][1] = __builtin_amdgcn_mfma_f32_16x16x32_bf16(a0, b1, acc[0][1], 0, 0, 0);
      acc[1][0] = __builtin_amdgcn_mfma_f32_16x16x32_bf16(a1, b0, acc[1][0], 0, 0, 0);
      acc[1][1] = __builtin_amdgcn_mfma_f32_16x16x32_bf16(a1, b1, acc[1][1], 0, 0, 0);
    }

    // cell epilogue: reunite 4 gates across the 4 gate-lanes (lr&3)
    #pragma unroll
    for (int mi = 0; mi < 2; mi++)
      #pragma unroll
      for (int ni = 0; ni < 2; ni++)
        #pragma unroll
        for (int j = 0; j < 4; j++){
          float v = acc[mi][ni][j] + bb[ni];
          float va = v;
          float vb = __shfl_xor(v, 1);
          float vc = __shfl_xor(v, 2);
          float vd = __shfl_xor(vb, 2);
          bool s1 = (lr & 1), s2 = (lr & 2);
          float P1 = s2 ? vc : va, P2 = s2 ? vd : vb;
          float Q1 = s2 ? va : vc, Q2 = s2 ? vb : vd;
          float gi  = s1 ? P2 : P1;
          float gf  = s1 ? P1 : P2;
          float gg  = s1 ? Q2 : Q1;
          float go_ = s1 ? Q1 : Q2;
          float c2 = sigm(gf) * creg[mi][ni][j] + sigm(gi) * tanh_f(gg);
          float h2 = sigm(go_) * tanh_f(c2);
          creg[mi][ni][j] = c2;
          unsigned short hb = f2b(h2);
          int row = w * 32 + mi * 16 + lg * 4 + j;
          int hl = ni * 4 + hw0;
          if ((lr & 3) == 0) chunk[row * 8 + hl][t & 15] = hb;                 // LDS, block-local
          if ((lr & 3) == 1) hout[(size_t)row * 1024 + blk * 8 + hl] = hb;     // 0.5MB/step global
        }

    // dump 16-step chunk to ys (contiguous 32B per row)
    if ((t & 15) == 15){
      __syncthreads();
      int t0 = t - 15;
      for (int r = tid; r < 2048; r += 512){
        int b = r >> 3, hl = r & 7;
        uint2 p0 = *(const uint2*)&chunk[r][0];
        uint2 p1 = *(const uint2*)&chunk[r][4];
        uint2 p2 = *(const uint2*)&chunk[r][8];
        uint2 p3 = *(const uint2*)&chunk[r][12];
        size_t o = ((size_t)b * 1024 + blk * 8 + hl) * 256 + t0;
        *(uint4*)&ys[o]     = (uint4){p0.x, p0.y, p1.x, p1.y};
        *(uint4*)&ys[o + 8] = (uint4){p2.x, p2.y, p3.x, p3.y};
      }
    }

    if (t < 255){
      __threadfence();      // release: my h-writes drained / L2 wb
      __syncthreads();
      if (tid == 0){
        __hip_atomic_fetch_add(&cnt[t], 1u, __ATOMIC_RELAXED, __HIP_MEMORY_SCOPE_AGENT);
        if (blk == 0){
          int spin = 0;
          while (__hip_atomic_fetch_add(&cnt[t], 0u, __ATOMIC_RELAXED,
                                        __HIP_MEMORY_SCOPE_AGENT) < (unsigned)NBLK
                 && spin < (1 << 16)){
            __builtin_amdgcn_s_sleep(2);
            ++spin;
          }
          __builtin_amdgcn_fence(__ATOMIC_ACQ_REL, "agent");
          for (int b = 1; b < NBLK; b++)
            __hip_atomic_store(&flagv[b * 32], (unsigned)t, __ATOMIC_RELAXED,
                               __HIP_MEMORY_SCOPE_AGENT);
        } else {
          int spin = 0;
          while ((int)__hip_atomic_fetch_add(&flagv[blk * 32], 0u, __ATOMIC_RELAXED,
                                             __HIP_MEMORY_SCOPE_AGENT) < t
                 && spin < (1 << 16)){
            __builtin_amdgcn_s_sleep(2);
            ++spin;
          }
          __builtin_amdgcn_fence(__ATOMIC_ACQUIRE, "agent");
        }
      }
      __syncthreads();
    }
  }
}

// ---- column stats (sum, sumsq), stage 1 ----
template<int C>
__global__ __launch_bounds__(256) void stats1(
    const unsigned short* __restrict__ X, float* __restrict__ psum, float* __restrict__ psq)
{
  int col = blockIdx.x * 256 + threadIdx.x;
  int r0 = blockIdx.y * 256;
  float s = 0.f, q = 0.f;
  for (int r = r0; r < r0 + 256; r++){
    float v = b2f(X[(size_t)r * C + col]);
    s += v; q += v * v;
  }
  psum[(size_t)blockIdx.y * C + col] = s;
  psq [(size_t)blockIdx.y * C + col] = q;
}

__global__ __launch_bounds__(256) void stats2(
    const float* __restrict__ psum, const float* __restrict__ psq,
    const float* __restrict__ g, const float* __restrict__ b,
    float* __restrict__ alpha, float* __restrict__ beta, int C)
{
  int c = blockIdx.x * 256 + threadIdx.x;
  if (c >= C) return;
  float s = 0.f, q = 0.f;
  for (int i = 0; i < 256; i++){ s += psum[(size_t)i * C + c]; q += psq[(size_t)i * C + c]; }
  float m = s * (1.f / 65536.f);
  float var = q * (1.f / 65536.f) - m * m; if (var < 0.f) var = 0.f;
  float a = g[c] * rsqrtf(var + 1e-5f);
  alpha[c] = a; beta[c] = b[c] - m * a;
}

// ---- fold BN into weights ----
template<int K>
__global__ __launch_bounds__(256) void foldk(
    const float* __restrict__ W, const float* __restrict__ bias,
    const float* __restrict__ alpha, const float* __restrict__ beta,
    unsigned short* __restrict__ Wb, float* __restrict__ bp, int rows)
{
  __shared__ float red[4];
  int o = blockIdx.x, t = threadIdx.x;
  float acc = 0.f;
  if (o < rows){
    for (int j = t; j < K; j += 256){
      float wv = W[(size_t)o * K + j];
      acc += beta[j] * wv;
      Wb[(size_t)o * K + j] = f2b(wv * alpha[j]);
    }
  } else {
    for (int j = t; j < K; j += 256) Wb[(size_t)o * K + j] = 0;
  }
  for (int off = 32; off > 0; off >>= 1) acc += __shfl_down(acc, off, 64);
  if ((t & 63) == 0) red[t >> 6] = acc;
  __syncthreads();
  if (t == 0) bp[o] = (o < rows ? bias[o] : 0.f) + red[0] + red[1] + red[2] + red[3];
}

// ---- final softmax with raw-reshape index mixing ----
__global__ __launch_bounds__(256) void softmax_k(
    const unsigned short* __restrict__ o3p, float* __restrict__ out)
{
  __shared__ unsigned short tile[25600];
  int b = blockIdx.x, t = threadIdx.x;
  const unsigned short* src = o3p + (size_t)b * 256 * 128;
  for (int i = t; i < 25600; i += 256){
    int rr = i / 100, nc = i - rr * 100;
    tile[i] = src[rr * 128 + nc];
  }
  __syncthreads();
  int v = t;
  float mx = -1e30f;
  for (int u = 0; u < 100; u++) mx = fmaxf(mx, b2f(tile[u * 256 + v]));
  float s = 0.f;
  for (int u = 0; u < 100; u++) s += __expf(b2f(tile[u * 256 + v]) - mx);
  float inv = 1.f / s;
  float* dst = out + (size_t)b * 25600;
  for (int u = 0; u < 100; u++)
    dst[u * 256 + v] = __expf(b2f(tile[u * 256 + v]) - mx) * inv;
}

extern "C" void kernel_launch(void* const* d_in, const int* in_sizes, int n_in,
                              void* d_out, int out_size, void* d_ws, size_t ws_size,
                              hipStream_t stream)
{
  (void)in_sizes; (void)n_in;
  const float* z     = (const float*)d_in[0];
  const float* Wzh   = (const float*)d_in[1];
  const float* bzh   = (const float*)d_in[2];
  const float* Wzc   = (const float*)d_in[3];
  const float* bzc   = (const float*)d_in[4];
  const float* g_bnzh= (const float*)d_in[5];
  const float* b_bnzh= (const float*)d_in[6];
  const float* g_bnzc= (const float*)d_in[7];
  const float* b_bnzc= (const float*)d_in[8];
  const float* Wih   = (const float*)d_in[9];
  const float* bih   = (const float*)d_in[10];
  const float* Whh   = (const float*)d_in[11];
  const float* bhh   = (const float*)d_in[12];
  const float* g_bn0 = (const float*)d_in[13];
  const float* b_bn0 = (const float*)d_in[14];
  const float* W1    = (const float*)d_in[15];
  const float* b1    = (const float*)d_in[16];
  const float* g_bn1 = (const float*)d_in[17];
  const float* b_bn1 = (const float*)d_in[18];
  const float* W2    = (const float*)d_in[19];
  const float* b2    = (const float*)d_in[20];
  const float* g_bn2 = (const float*)d_in[21];
  const float* b_bn2 = (const float*)d_in[22];
  const float* W3    = (const float*)d_in[23];
  const float* b3    = (const float*)d_in[24];
  const float* go    = (const float*)d_in[25];

  char* base = (char*)d_ws;
  size_t off = 0;
  auto alloc = [&](size_t bytes)->char*{
    char* p = base + off;
    off = (off + bytes + 255) & ~(size_t)255;
    return p;
  };
  const size_t MB = 1024 * 1024;

  unsigned short* ys = (unsigned short*)alloc(128 * MB);  // [b*1024+h][256] bf16
  unsigned short* o1 = (unsigned short*)alloc(64 * MB);   // [65536][512] bf16
  char* zone = alloc(32 * MB);                            // dead after LSTM; o2 overlays
  unsigned short* Wsum_p = (unsigned short*)(zone);            // 8 MB
  unsigned short* Whh_b  = (unsigned short*)(zone + 8 * MB);   // 8 MB
  float*          gates0 = (float*)(zone + 16 * MB);           // 4 MB
  // persistent-small region
  float* zh_raw = (float*)alloc(1 * MB);
  float* zc_raw = (float*)alloc(1 * MB);
  float* bias_sp = (float*)alloc(16384);
  float* bias0   = (float*)alloc(16384);
  unsigned short* zh_b  = (unsigned short*)alloc((size_t)256 * 1024 * 2);
  unsigned short* hbuf0 = (unsigned short*)alloc((size_t)256 * 1024 * 2);
  unsigned short* hbuf1 = (unsigned short*)alloc((size_t)256 * 1024 * 2);
  float* c_f    = (float*)alloc((size_t)256 * 1024 * 4);
  float* psum   = (float*)alloc(1 * MB);
  float* psq    = (float*)alloc(1 * MB);
  float* alpha0 = (float*)alloc(4096); float* beta0 = (float*)alloc(4096);
  float* alpha1 = (float*)alloc(4096); float* beta1 = (float*)alloc(4096);
  float* alpha2 = (float*)alloc(4096); float* beta2 = (float*)alloc(4096);
  unsigned short* W1b = (unsigned short*)alloc((size_t)512 * 1024 * 2);
  unsigned short* W2b = (unsigned short*)alloc((size_t)256 * 512 * 2);
  unsigned short* W3b = (unsigned short*)alloc((size_t)128 * 256 * 2);
  float* b1p = (float*)alloc(4096);
  float* b2p = (float*)alloc(4096);
  float* b3p = (float*)alloc(4096);
  unsigned int* cnt   = (unsigned int*)alloc(1024);    // cnt[256]
  unsigned int* flagv = (unsigned int*)alloc(16384);   // 128 flags, 128B stride
  unsigned short* o2  = (unsigned short*)zone;  // 32 MB overlays dead zone
  unsigned short* o3p = o1;                     // 16 MB overlays dead o1

  if (off > ws_size){
    zerofill<<<(out_size + 255) / 256, 256, 0, stream>>>((float*)d_out, out_size);
    return;
  }

  zerofill<<<18, 256, 0, stream>>>((float*)cnt, 256 + 4096);
  prep_w<<<16384, 256, 0, stream>>>(Wih, Whh, bih, bhh, Wsum_p, Whh_b, bias_sp);
  prep_b0<<<4096, 256, 0, stream>>>(Wih, go, bih, bhh, bias0);
  zproj<<<1024, 256, 0, stream>>>(z, Wzh, bzh, Wzc, bzc, zh_raw, zc_raw);
  bn_init<<<1024, 256, 0, stream>>>(zh_raw, zc_raw, g_bnzh, b_bnzh, g_bnzc, b_bnzc, zh_b, c_f);

  // step 0: gates0 = zh @ Whh^T + bias0(go-term folded); then cell
  gemm_bt2<1024, 0, 0><<<dim3(32, 4), 256, 0, stream>>>(zh_b, Whh_b, bias0, gates0, 4096);
  lstm_cell0<<<1024, 256, 0, stream>>>(gates0, c_f, hbuf0);

  // steps 1..255 in one persistent kernel
  lstm_persist<<<NBLK, 512, 0, stream>>>(Wsum_p, bias_sp, hbuf0, hbuf1, c_f, ys, cnt, flagv);

  stats1<1024><<<dim3(4, 256), 256, 0, stream>>>(ys, psum, psq);
  stats2<<<4, 256, 0, stream>>>(psum, psq, g_bn0, b_bn0, alpha0, beta0, 1024);
  foldk<1024><<<512, 256, 0, stream>>>(W1, b1, alpha0, beta0, W1b, b1p, 512);
  gemm_bt2<1024, 1, 1><<<dim3(4, 1024), 256, 0, stream>>>(ys, W1b, b1p, o1, 512);

  stats1<512><<<dim3(2, 256), 256, 0, stream>>>(o1, psum, psq);
  stats2<<<2, 256, 0, stream>>>(psum, psq, g_bn1, b_bn1, alpha1, beta1, 512);
  foldk<512><<<256, 256, 0, stream>>>(W2, b2, alpha1, beta1, W2b, b2p, 256);
  gemm_bt2<512, 1, 1><<<dim3(2, 1024), 256, 0, stream>>>(o1, W2b, b2p, o2, 256);

  stats1<256><<<dim3(1, 256), 256, 0, stream>>>(o2, psum, psq);
  stats2<<<1, 256, 0, stream>>>(psum, psq, g_bn2, b_bn2, alpha2, beta2, 256);
  foldk<256><<<128, 256, 0, stream>>>(W3, b3, alpha2, beta2, W3b, b3p, 100);
  gemm_bt2<256, 0, 1><<<dim3(1, 1024), 256, 0, stream>>>(o2, W3b, b3p, o3p, 128);

  softmax_k<<<256, 256, 0, stream>>>(o3p, (float*)d_out);
}

// Round 8
// 6611.252 us; speedup vs baseline: 2.7765x; 1.8386x over previous
//
#include <hip/hip_runtime.h>
#include <hip/hip_bf16.h>

typedef __attribute__((ext_vector_type(8))) short bf16x8;
typedef __attribute__((ext_vector_type(4))) float f32x4;

#define NBLK 128

__device__ inline unsigned short f2b(float x){
  union { float f; unsigned int u; } v; v.f = x;
  unsigned int u = v.u;
  return (unsigned short)((u + 0x7FFFu + ((u >> 16) & 1u)) >> 16);
}
__device__ inline float b2f(unsigned short h){
  union { unsigned int u; float f; } v; v.u = ((unsigned int)h) << 16; return v.f;
}
__device__ inline float sigm(float x){ return 1.f / (1.f + __expf(-x)); }
__device__ inline float tanh_f(float x){ float e2 = __expf(2.f * x); return 1.f - 2.f / (e2 + 1.f); }

__global__ __launch_bounds__(256) void zerofill(float* __restrict__ p, int n){
  int i = blockIdx.x * 256 + threadIdx.x;
  if (i < n) p[i] = 0.f;
}

// packed row for gate-row n = g*1024 + h:  blk = h>>3, local = (h&7)*4 + g
__device__ inline int packrow(int n){
  int g = n >> 10, h = n & 1023;
  return (h >> 3) * 32 + (h & 7) * 4 + g;
}

// ---- prep: Wsum as per-block LDS images (MFMA fragment order), Whh plain bf16, biases ----
__global__ __launch_bounds__(256) void prep_w(
    const float* __restrict__ Wih, const float* __restrict__ Whh,
    const float* __restrict__ bih, const float* __restrict__ bhh,
    unsigned short* __restrict__ Wsum_p, unsigned short* __restrict__ Whh_b,
    float* __restrict__ bias_sp)
{
  size_t idx = (size_t)blockIdx.x * 256 + threadIdx.x; // 4096*1024
  int n = (int)(idx >> 10), k = (int)(idx & 1023);
  int g = n >> 10, h = n & 1023;
  float wi = Wih[idx], wh = Whh[idx];
  int blk = h >> 3;
  int r  = ((h & 7) << 2) | g;         // local row 0..31
  int nt = r >> 4, lr2 = r & 15;
  int kb = k >> 5, lg2 = (k >> 3) & 3, e = k & 7;
  size_t dest = (size_t)blk * 32768 + (size_t)nt * 16384 + (size_t)kb * 512
              + (size_t)(lg2 * 16 + lr2) * 8 + e;
  Wsum_p[dest] = f2b(wi + wh);
  Whh_b[idx] = f2b(wh);
  if (idx < 4096) bias_sp[packrow((int)idx)] = bih[idx] + bhh[idx];
}

// bias0[n] (plain) = bih+bhh + sum_k W_ih[n,k]*go[0,k]
__global__ __launch_bounds__(256) void prep_b0(
    const float* __restrict__ Wih, const float* __restrict__ go,
    const float* __restrict__ bih, const float* __restrict__ bhh,
    float* __restrict__ bias0)
{
  __shared__ float red[4];
  int n = blockIdx.x, t = threadIdx.x;
  float acc = 0.f;
  for (int k = t; k < 1024; k += 256) acc += Wih[(size_t)n*1024 + k] * go[k];
  for (int off = 32; off > 0; off >>= 1) acc += __shfl_down(acc, off, 64);
  if ((t & 63) == 0) red[t >> 6] = acc;
  __syncthreads();
  if (t == 0) bias0[n] = bih[n] + bhh[n] + red[0] + red[1] + red[2] + red[3];
}

// ---- z projections (K=128, f32) ----
__global__ __launch_bounds__(256) void zproj(
    const float* __restrict__ z, const float* __restrict__ Wzh, const float* __restrict__ bzh,
    const float* __restrict__ Wzc, const float* __restrict__ bzc,
    float* __restrict__ zh_raw, float* __restrict__ zc_raw)
{
  int idx = blockIdx.x * 256 + threadIdx.x; // 256*1024
  int b = idx >> 10, c = idx & 1023;
  const float* zr = z + b * 128;
  const float* wh = Wzh + c * 128;
  const float* wc = Wzc + c * 128;
  float s1 = bzh[c], s2 = bzc[c];
  #pragma unroll 8
  for (int k = 0; k < 128; k++){ float zv = zr[k]; s1 += zv * wh[k]; s2 += zv * wc[k]; }
  zh_raw[idx] = s1; zc_raw[idx] = s2;
}

// ---- BN over batch: zh -> zh_b (bf16), zc -> c_f (f32) ----
__global__ __launch_bounds__(256) void bn_init(
    const float* __restrict__ zh_raw, const float* __restrict__ zc_raw,
    const float* __restrict__ g_h, const float* __restrict__ bt_h,
    const float* __restrict__ g_c, const float* __restrict__ bt_c,
    unsigned short* __restrict__ zh_b, float* __restrict__ c_f)
{
  __shared__ float red[4][4];
  int c = blockIdx.x, r = threadIdx.x;
  float v1 = zh_raw[r * 1024 + c];
  float v2 = zc_raw[r * 1024 + c];
  float s[4] = { v1, v1*v1, v2, v2*v2 };
  #pragma unroll
  for (int i = 0; i < 4; i++){
    float x = s[i];
    for (int off = 32; off > 0; off >>= 1) x += __shfl_down(x, off, 64);
    if ((r & 63) == 0) red[i][r >> 6] = x;
  }
  __syncthreads();
  float m1 = (red[0][0]+red[0][1]+red[0][2]+red[0][3]) * (1.f/256.f);
  float q1 = (red[1][0]+red[1][1]+red[1][2]+red[1][3]) * (1.f/256.f);
  float m2 = (red[2][0]+red[2][1]+red[2][2]+red[2][3]) * (1.f/256.f);
  float q2 = (red[3][0]+red[3][1]+red[3][2]+red[3][3]) * (1.f/256.f);
  float var1 = q1 - m1*m1; if (var1 < 0.f) var1 = 0.f;
  float var2 = q2 - m2*m2; if (var2 < 0.f) var2 = 0.f;
  float a1 = g_h[c] * rsqrtf(var1 + 1e-5f), be1 = bt_h[c] - m1*a1;
  float a2 = g_c[c] * rsqrtf(var2 + 1e-5f), be2 = bt_c[c] - m2*a2;
  zh_b[r * 1024 + c] = f2b(v1*a1 + be1);
  c_f[r * 1024 + c] = v2*a2 + be2;
}

// ---- MLP / step0 GEMM: out[M][N] = A[M][K] @ B[N][K]^T + bias; 64x128 tile ----
template<int K, int ACT, int OBF16>
__global__ __launch_bounds__(256) void gemm_bt2(
    const unsigned short* __restrict__ A, const unsigned short* __restrict__ B,
    const float* __restrict__ bias, void* __restrict__ outp, int N)
{
  const int tid = threadIdx.x;
  const int w = tid >> 6, l = tid & 63;
  const int lr = l & 15, lg = l >> 4;
  const int m0 = blockIdx.y * 64 + (w >> 1) * 32;
  const int n0 = blockIdx.x * 128 + (w & 1) * 64;
  f32x4 acc[2][4];
  #pragma unroll
  for (int i = 0; i < 2; i++)
    #pragma unroll
    for (int j = 0; j < 4; j++) acc[i][j] = (f32x4){0.f,0.f,0.f,0.f};

  const unsigned short* pa0 = A + (size_t)(m0 + lr) * K + lg * 8;
  const unsigned short* pa1 = pa0 + (size_t)16 * K;
  const unsigned short* pb0 = B + (size_t)(n0 + lr) * K + lg * 8;

  for (int kb = 0; kb < K; kb += 32){
    bf16x8 a0 = *(const bf16x8*)(pa0 + kb);
    bf16x8 a1 = *(const bf16x8*)(pa1 + kb);
    bf16x8 b0 = *(const bf16x8*)(pb0 + kb);
    bf16x8 b1 = *(const bf16x8*)(pb0 + (size_t)16 * K + kb);
    bf16x8 b2 = *(const bf16x8*)(pb0 + (size_t)32 * K + kb);
    bf16x8 b3 = *(const bf16x8*)(pb0 + (size_t)48 * K + kb);
    acc[0][0] = __builtin_amdgcn_mfma_f32_16x16x32_bf16(a0, b0, acc[0][0], 0, 0, 0);
    acc[0][1] = __builtin_amdgcn_mfma_f32_16x16x32_bf16(a0, b1, acc[0][1], 0, 0, 0);
    acc[0][2] = __builtin_amdgcn_mfma_f32_16x16x32_bf16(a0, b2, acc[0][2], 0, 0, 0);
    acc[0][3] = __builtin_amdgcn_mfma_f32_16x16x32_bf16(a0, b3, acc[0][3], 0, 0, 0);
    acc[1][0] = __builtin_amdgcn_mfma_f32_16x16x32_bf16(a1, b0, acc[1][0], 0, 0, 0);
    acc[1][1] = __builtin_amdgcn_mfma_f32_16x16x32_bf16(a1, b1, acc[1][1], 0, 0, 0);
    acc[1][2] = __builtin_amdgcn_mfma_f32_16x16x32_bf16(a1, b2, acc[1][2], 0, 0, 0);
    acc[1][3] = __builtin_amdgcn_mfma_f32_16x16x32_bf16(a1, b3, acc[1][3], 0, 0, 0);
  }

  #pragma unroll
  for (int mi = 0; mi < 2; mi++)
    #pragma unroll
    for (int ni = 0; ni < 4; ni++){
      int col = n0 + ni * 16 + lr;
      float bs = bias[col];
      #pragma unroll
      for (int j = 0; j < 4; j++){
        int row = m0 + mi * 16 + lg * 4 + j;
        float v = acc[mi][ni][j] + bs;
        if (ACT) v = v > 0.f ? v : 0.01f * v;
        if (OBF16) ((unsigned short*)outp)[(size_t)row * N + col] = f2b(v);
        else       ((float*)outp)[(size_t)row * N + col] = v;
      }
    }
}

// ---- step-0 cell: gates0 -> c, h(0) into hbuf0 ----
__global__ __launch_bounds__(256) void lstm_cell0(
    const float* __restrict__ gates, float* __restrict__ c,
    unsigned short* __restrict__ hbuf0)
{
  int idx = blockIdx.x * 256 + threadIdx.x; // 256*1024
  int b = idx >> 10, h = idx & 1023;
  const float* g = gates + (size_t)b * 4096;
  float ig = g[h], fg = g[1024 + h], gg = g[2048 + h], og = g[3072 + h];
  float co = c[idx];
  float c2 = sigm(fg) * co + sigm(ig) * tanh_f(gg);
  float h2 = sigm(og) * tanh_f(c2);
  c[idx] = c2;
  hbuf0[idx] = f2b(h2);
}

// ---- persistent LSTM: steps 1..255, fully parallel grid barrier, coherent h stores ----
// 128 blocks x 512 threads. Block blk owns h-cols [blk*8, blk*8+8) = 32 packed gate-rows.
__global__ __launch_bounds__(512, 1) void lstm_persist(
    const unsigned short* __restrict__ Wp, const float* __restrict__ bias_sp,
    unsigned short* __restrict__ hbuf0, unsigned short* __restrict__ hbuf1,
    const float* __restrict__ c_init, unsigned short* __restrict__ ys,
    unsigned int* __restrict__ arr, unsigned int* __restrict__ flagv)
{
  __shared__ unsigned short Wl[32768];        // 64 KB: fragment-order image, conflict-free
  __shared__ unsigned short chunk[2048][20];  // 80 KB: [b*8+hl][t&15] (+pad), 16-step ys chunk
  const int tid = threadIdx.x;
  const int blk = blockIdx.x;
  const int w = tid >> 6, l = tid & 63;
  const int lr = l & 15, lg = l >> 4;

  // stage W image: contiguous copy (layout prebaked by prep_w)
  {
    const bf16x8* src = (const bf16x8*)(Wp + (size_t)blk * 32768);
    bf16x8* dst = (bf16x8*)Wl;
    for (int i = tid; i < 4096; i += 512) dst[i] = src[i];
  }
  // preload t=0 h into chunk slot 0 (written by lstm_cell0 into hbuf0)
  for (int i = tid; i < 2048; i += 512){
    int b = i >> 3, hl = i & 7;
    chunk[i][0] = hbuf0[(size_t)b * 1024 + blk * 8 + hl];
  }

  const int hw0 = lr >> 2;
  float bb[2];
  bb[0] = bias_sp[blk * 32 + lr];
  bb[1] = bias_sp[blk * 32 + 16 + lr];

  float creg[2][2][4];
  #pragma unroll
  for (int mi = 0; mi < 2; mi++)
    #pragma unroll
    for (int ni = 0; ni < 2; ni++)
      #pragma unroll
      for (int j = 0; j < 4; j++){
        int row = w * 32 + mi * 16 + lg * 4 + j;
        int h = blk * 8 + ni * 4 + hw0;
        creg[mi][ni][j] = c_init[(size_t)row * 1024 + h];
      }

  __syncthreads();

  const char* lwb = (const char*)Wl + l * 16;

  #pragma unroll 1
  for (int t = 1; t < 256; t++){
    const unsigned short* hin = (t & 1) ? hbuf0 : hbuf1;
    unsigned int* hout32 = (unsigned int*)((t & 1) ? hbuf1 : hbuf0);

    f32x4 acc[2][2];
    #pragma unroll
    for (int i = 0; i < 2; i++)
      #pragma unroll
      for (int j = 0; j < 2; j++) acc[i][j] = (f32x4){0.f,0.f,0.f,0.f};

    const unsigned short* pa0 = hin + (size_t)(w * 32 + lr) * 1024 + lg * 8;
    const unsigned short* pa1 = pa0 + 16 * 1024;

    #pragma unroll 8
    for (int kb = 0; kb < 32; kb++){
      bf16x8 a0 = *(const bf16x8*)(pa0 + kb * 32);
      bf16x8 a1 = *(const bf16x8*)(pa1 + kb * 32);
      bf16x8 b0 = *(const bf16x8*)(lwb + kb * 1024);
      bf16x8 b1 = *(const bf16x8*)(lwb + 32768 + kb * 1024);
      acc[0][0] = __builtin_amdgcn_mfma_f32_16x16x32_bf16(a0, b0, acc[0][0], 0, 0, 0);
      acc[0][1] = __builtin_amdgcn_mfma_f32_16x16x32_bf16(a0, b1, acc[0][1], 0, 0, 0);
      acc[1][0] = __builtin_amdgcn_mfma_f32_16x16x32_bf16(a1, b0, acc[1][0], 0, 0, 0);
      acc[1][1] = __builtin_amdgcn_mfma_f32_16x16x32_bf16(a1, b1, acc[1][1], 0, 0, 0);
    }

    // cell epilogue: reunite 4 gates across the 4 gate-lanes (lr&3)
    #pragma unroll
    for (int mi = 0; mi < 2; mi++)
      #pragma unroll
      for (int ni = 0; ni < 2; ni++)
        #pragma unroll
        for (int j = 0; j < 4; j++){
          float v = acc[mi][ni][j] + bb[ni];
          float va = v;
          float vb = __shfl_xor(v, 1);
          float vc = __shfl_xor(v, 2);
          float vd = __shfl_xor(vb, 2);
          bool s1 = (lr & 1), s2 = (lr & 2);
          float P1 = s2 ? vc : va, P2 = s2 ? vd : vb;
          float Q1 = s2 ? va : vc, Q2 = s2 ? vb : vd;
          float gi  = s1 ? P2 : P1;
          float gf  = s1 ? P1 : P2;
          float gg  = s1 ? Q2 : Q1;
          float go_ = s1 ? Q1 : Q2;
          float c2 = sigm(gf) * creg[mi][ni][j] + sigm(gi) * tanh_f(gg);
          float h2 = sigm(go_) * tanh_f(c2);
          creg[mi][ni][j] = c2;
          unsigned short hb = f2b(h2);
          int row = w * 32 + mi * 16 + lg * 4 + j;
          int hl = ni * 4 + hw0;
          if ((lr & 3) == 0) chunk[row * 8 + hl][t & 15] = hb;  // LDS, block-local (ys path)
          // coherent h-out: pair (hl, hl+1) into one dword, atomicExch to coherence point
          unsigned int pv = (unsigned int)(unsigned short)__shfl_xor((int)hb, 4);
          if ((lr & 7) == 1){
            unsigned int val = (pv << 16) | (unsigned int)hb;
            atomicExch(&hout32[row * 512 + blk * 4 + ni * 2 + (hw0 >> 1)], val);
          }
        }

    // dump 16-step chunk to ys (contiguous 32B per row; stays in L2, flushed at kernel end)
    if ((t & 15) == 15){
      __syncthreads();
      int t0 = t - 15;
      for (int r = tid; r < 2048; r += 512){
        int b = r >> 3, hl = r & 7;
        uint2 p0 = *(const uint2*)&chunk[r][0];
        uint2 p1 = *(const uint2*)&chunk[r][4];
        uint2 p2 = *(const uint2*)&chunk[r][8];
        uint2 p3 = *(const uint2*)&chunk[r][12];
        size_t o = ((size_t)b * 1024 + blk * 8 + hl) * 256 + t0;
        *(uint4*)&ys[o]     = (uint4){p0.x, p0.y, p1.x, p1.y};
        *(uint4*)&ys[o + 8] = (uint4){p2.x, p2.y, p3.x, p3.y};
      }
    }

    if (t < 255){
      __syncthreads();   // vmcnt(0) drain: all atomicExch h-stores committed
      if (blk == 0){
        if (tid == 0)
          __hip_atomic_fetch_add(&arr[0], 1u, __ATOMIC_RELAXED, __HIP_MEMORY_SCOPE_AGENT);
        if (tid < NBLK){
          int spin = 0;
          while (__hip_atomic_fetch_add(&arr[tid * 32], 0u, __ATOMIC_RELAXED,
                                        __HIP_MEMORY_SCOPE_AGENT) < (unsigned)t
                 && spin < (1 << 16)){
            __builtin_amdgcn_s_sleep(1);
            ++spin;
          }
        }
        __syncthreads();  // all 128 arrivals observed
        if (tid >= 1 && tid < NBLK)
          __hip_atomic_fetch_add(&flagv[tid * 32], 1u, __ATOMIC_RELAXED,
                                 __HIP_MEMORY_SCOPE_AGENT);
      } else {
        if (tid == 0){
          __hip_atomic_fetch_add(&arr[blk * 32], 1u, __ATOMIC_RELAXED,
                                 __HIP_MEMORY_SCOPE_AGENT);
          int spin = 0;
          while (__hip_atomic_fetch_add(&flagv[blk * 32], 0u, __ATOMIC_RELAXED,
                                        __HIP_MEMORY_SCOPE_AGENT) < (unsigned)t
                 && spin < (1 << 16)){
            __builtin_amdgcn_s_sleep(1);
            ++spin;
          }
        }
      }
      if (tid == 0) __builtin_amdgcn_fence(__ATOMIC_ACQUIRE, "agent"); // inv L1/L2
      __syncthreads();
    }
  }
}

// ---- column stats (sum, sumsq), stage 1 ----
template<int C>
__global__ __launch_bounds__(256) void stats1(
    const unsigned short* __restrict__ X, float* __restrict__ psum, float* __restrict__ psq)
{
  int col = blockIdx.x * 256 + threadIdx.x;
  int r0 = blockIdx.y * 256;
  float s = 0.f, q = 0.f;
  for (int r = r0; r < r0 + 256; r++){
    float v = b2f(X[(size_t)r * C + col]);
    s += v; q += v * v;
  }
  psum[(size_t)blockIdx.y * C + col] = s;
  psq [(size_t)blockIdx.y * C + col] = q;
}

__global__ __launch_bounds__(256) void stats2(
    const float* __restrict__ psum, const float* __restrict__ psq,
    const float* __restrict__ g, const float* __restrict__ b,
    float* __restrict__ alpha, float* __restrict__ beta, int C)
{
  int c = blockIdx.x * 256 + threadIdx.x;
  if (c >= C) return;
  float s = 0.f, q = 0.f;
  for (int i = 0; i < 256; i++){ s += psum[(size_t)i * C + c]; q += psq[(size_t)i * C + c]; }
  float m = s * (1.f / 65536.f);
  float var = q * (1.f / 65536.f) - m * m; if (var < 0.f) var = 0.f;
  float a = g[c] * rsqrtf(var + 1e-5f);
  alpha[c] = a; beta[c] = b[c] - m * a;
}

// ---- fold BN into weights ----
template<int K>
__global__ __launch_bounds__(256) void foldk(
    const float* __restrict__ W, const float* __restrict__ bias,
    const float* __restrict__ alpha, const float* __restrict__ beta,
    unsigned short* __restrict__ Wb, float* __restrict__ bp, int rows)
{
  __shared__ float red[4];
  int o = blockIdx.x, t = threadIdx.x;
  float acc = 0.f;
  if (o < rows){
    for (int j = t; j < K; j += 256){
      float wv = W[(size_t)o * K + j];
      acc += beta[j] * wv;
      Wb[(size_t)o * K + j] = f2b(wv * alpha[j]);
    }
  } else {
    for (int j = t; j < K; j += 256) Wb[(size_t)o * K + j] = 0;
  }
  for (int off = 32; off > 0; off >>= 1) acc += __shfl_down(acc, off, 64);
  if ((t & 63) == 0) red[t >> 6] = acc;
  __syncthreads();
  if (t == 0) bp[o] = (o < rows ? bias[o] : 0.f) + red[0] + red[1] + red[2] + red[3];
}

// ---- final softmax with raw-reshape index mixing ----
__global__ __launch_bounds__(256) void softmax_k(
    const unsigned short* __restrict__ o3p, float* __restrict__ out)
{
  __shared__ unsigned short tile[25600];
  int b = blockIdx.x, t = threadIdx.x;
  const unsigned short* src = o3p + (size_t)b * 256 * 128;
  for (int i = t; i < 25600; i += 256){
    int rr = i / 100, nc = i - rr * 100;
    tile[i] = src[rr * 128 + nc];
  }
  __syncthreads();
  int v = t;
  float mx = -1e30f;
  for (int u = 0; u < 100; u++) mx = fmaxf(mx, b2f(tile[u * 256 + v]));
  float s = 0.f;
  for (int u = 0; u < 100; u++) s += __expf(b2f(tile[u * 256 + v]) - mx);
  float inv = 1.f / s;
  float* dst = out + (size_t)b * 25600;
  for (int u = 0; u < 100; u++)
    dst[u * 256 + v] = __expf(b2f(tile[u * 256 + v]) - mx) * inv;
}

extern "C" void kernel_launch(void* const* d_in, const int* in_sizes, int n_in,
                              void* d_out, int out_size, void* d_ws, size_t ws_size,
                              hipStream_t stream)
{
  (void)in_sizes; (void)n_in;
  const float* z     = (const float*)d_in[0];
  const float* Wzh   = (const float*)d_in[1];
  const float* bzh   = (const float*)d_in[2];
  const float* Wzc   = (const float*)d_in[3];
  const float* bzc   = (const float*)d_in[4];
  const float* g_bnzh= (const float*)d_in[5];
  const float* b_bnzh= (const float*)d_in[6];
  const float* g_bnzc= (const float*)d_in[7];
  const float* b_bnzc= (const float*)d_in[8];
  const float* Wih   = (const float*)d_in[9];
  const float* bih   = (const float*)d_in[10];
  const float* Whh   = (const float*)d_in[11];
  const float* bhh   = (const float*)d_in[12];
  const float* g_bn0 = (const float*)d_in[13];
  const float* b_bn0 = (const float*)d_in[14];
  const float* W1    = (const float*)d_in[15];
  const float* b1    = (const float*)d_in[16];
  const float* g_bn1 = (const float*)d_in[17];
  const float* b_bn1 = (const float*)d_in[18];
  const float* W2    = (const float*)d_in[19];
  const float* b2    = (const float*)d_in[20];
  const float* g_bn2 = (const float*)d_in[21];
  const float* b_bn2 = (const float*)d_in[22];
  const float* W3    = (const float*)d_in[23];
  const float* b3    = (const float*)d_in[24];
  const float* go    = (const float*)d_in[25];

  char* base = (char*)d_ws;
  size_t off = 0;
  auto alloc = [&](size_t bytes)->char*{
    char* p = base + off;
    off = (off + bytes + 255) & ~(size_t)255;
    return p;
  };
  const size_t MB = 1024 * 1024;

  unsigned short* ys = (unsigned short*)alloc(128 * MB);  // [b*1024+h][256] bf16
  unsigned short* o1 = (unsigned short*)alloc(64 * MB);   // [65536][512] bf16
  char* zone = alloc(32 * MB);                            // dead after LSTM; o2 overlays
  unsigned short* Wsum_p = (unsigned short*)(zone);            // 8 MB
  unsigned short* Whh_b  = (unsigned short*)(zone + 8 * MB);   // 8 MB
  float*          gates0 = (float*)(zone + 16 * MB);           // 4 MB
  // persistent-small region
  float* zh_raw = (float*)alloc(1 * MB);
  float* zc_raw = (float*)alloc(1 * MB);
  float* bias_sp = (float*)alloc(16384);
  float* bias0   = (float*)alloc(16384);
  unsigned short* zh_b  = (unsigned short*)alloc((size_t)256 * 1024 * 2);
  unsigned short* hbuf0 = (unsigned short*)alloc((size_t)256 * 1024 * 2);
  unsigned short* hbuf1 = (unsigned short*)alloc((size_t)256 * 1024 * 2);
  float* c_f    = (float*)alloc((size_t)256 * 1024 * 4);
  float* psum   = (float*)alloc(1 * MB);
  float* psq    = (float*)alloc(1 * MB);
  float* alpha0 = (float*)alloc(4096); float* beta0 = (float*)alloc(4096);
  float* alpha1 = (float*)alloc(4096); float* beta1 = (float*)alloc(4096);
  float* alpha2 = (float*)alloc(4096); float* beta2 = (float*)alloc(4096);
  unsigned short* W1b = (unsigned short*)alloc((size_t)512 * 1024 * 2);
  unsigned short* W2b = (unsigned short*)alloc((size_t)256 * 512 * 2);
  unsigned short* W3b = (unsigned short*)alloc((size_t)128 * 256 * 2);
  float* b1p = (float*)alloc(4096);
  float* b2p = (float*)alloc(4096);
  float* b3p = (float*)alloc(4096);
  unsigned int* arr   = (unsigned int*)alloc(16384);   // 128 arrival counters, 128B stride
  unsigned int* flagv = (unsigned int*)alloc(16384);   // 128 flags, 128B stride
  unsigned short* o2  = (unsigned short*)zone;  // 32 MB overlays dead zone
  unsigned short* o3p = o1;                     // 16 MB overlays dead o1

  if (off > ws_size){
    zerofill<<<(out_size + 255) / 256, 256, 0, stream>>>((float*)d_out, out_size);
    return;
  }

  zerofill<<<32, 256, 0, stream>>>((float*)arr, 8192);
  prep_w<<<16384, 256, 0, stream>>>(Wih, Whh, bih, bhh, Wsum_p, Whh_b, bias_sp);
  prep_b0<<<4096, 256, 0, stream>>>(Wih, go, bih, bhh, bias0);
  zproj<<<1024, 256, 0, stream>>>(z, Wzh, bzh, Wzc, bzc, zh_raw, zc_raw);
  bn_init<<<1024, 256, 0, stream>>>(zh_raw, zc_raw, g_bnzh, b_bnzh, g_bnzc, b_bnzc, zh_b, c_f);

  // step 0: gates0 = zh @ Whh^T + bias0(go-term folded); then cell
  gemm_bt2<1024, 0, 0><<<dim3(32, 4), 256, 0, stream>>>(zh_b, Whh_b, bias0, gates0, 4096);
  lstm_cell0<<<1024, 256, 0, stream>>>(gates0, c_f, hbuf0);

  // steps 1..255 in one persistent kernel
  lstm_persist<<<NBLK, 512, 0, stream>>>(Wsum_p, bias_sp, hbuf0, hbuf1, c_f, ys, arr, flagv);

  stats1<1024><<<dim3(4, 256), 256, 0, stream>>>(ys, psum, psq);
  stats2<<<4, 256, 0, stream>>>(psum, psq, g_bn0, b_bn0, alpha0, beta0, 1024);
  foldk<1024><<<512, 256, 0, stream>>>(W1, b1, alpha0, beta0, W1b, b1p, 512);
  gemm_bt2<1024, 1, 1><<<dim3(4, 1024), 256, 0, stream>>>(ys, W1b, b1p, o1, 512);

  stats1<512><<<dim3(2, 256), 256, 0, stream>>>(o1, psum, psq);
  stats2<<<2, 256, 0, stream>>>(psum, psq, g_bn1, b_bn1, alpha1, beta1, 512);
  foldk<512><<<256, 256, 0, stream>>>(W2, b2, alpha1, beta1, W2b, b2p, 256);
  gemm_bt2<512, 1, 1><<<dim3(2, 1024), 256, 0, stream>>>(o1, W2b, b2p, o2, 256);

  stats1<256><<<dim3(1, 256), 256, 0, stream>>>(o2, psum, psq);
  stats2<<<1, 256, 0, stream>>>(psum, psq, g_bn2, b_bn2, alpha2, beta2, 256);
  foldk<256><<<128, 256, 0, stream>>>(W3, b3, alpha2, beta2, W3b, b3p, 100);
  gemm_bt2<256, 0, 1><<<dim3(1, 1024), 256, 0, stream>>>(o2, W3b, b3p, o3p, 128);

  softmax_k<<<256, 256, 0, stream>>>(o3p, (float*)d_out);
}

// Round 9
// 5189.022 us; speedup vs baseline: 3.5375x; 1.2741x over previous
//
#include <hip/hip_runtime.h>
#include <hip/hip_bf16.h>

typedef __attribute__((ext_vector_type(8))) short bf16x8;
typedef __attribute__((ext_vector_type(4))) float f32x4;

#define NBLK 256   // 2 M-halves x 128 h-tiles

__device__ inline unsigned short f2b(float x){
  union { float f; unsigned int u; } v; v.f = x;
  unsigned int u = v.u;
  return (unsigned short)((u + 0x7FFFu + ((u >> 16) & 1u)) >> 16);
}
__device__ inline float b2f(unsigned short h){
  union { unsigned int u; float f; } v; v.u = ((unsigned int)h) << 16; return v.f;
}
__device__ inline float sigm(float x){ return 1.f / (1.f + __expf(-x)); }
__device__ inline float tanh_f(float x){ float e2 = __expf(2.f * x); return 1.f - 2.f / (e2 + 1.f); }

__global__ __launch_bounds__(256) void zerofill(float* __restrict__ p, int n){
  int i = blockIdx.x * 256 + threadIdx.x;
  if (i < n) p[i] = 0.f;
}

// packed row for gate-row n = g*1024 + h:  htile = h>>3, local = (h&7)*4 + g
__device__ inline int packrow(int n){
  int g = n >> 10, h = n & 1023;
  return (h >> 3) * 32 + (h & 7) * 4 + g;
}

// ---- prep: Wsum as per-htile LDS images (MFMA fragment order), Whh plain bf16, biases ----
__global__ __launch_bounds__(256) void prep_w(
    const float* __restrict__ Wih, const float* __restrict__ Whh,
    const float* __restrict__ bih, const float* __restrict__ bhh,
    unsigned short* __restrict__ Wsum_p, unsigned short* __restrict__ Whh_b,
    float* __restrict__ bias_sp)
{
  size_t idx = (size_t)blockIdx.x * 256 + threadIdx.x; // 4096*1024
  int n = (int)(idx >> 10), k = (int)(idx & 1023);
  int g = n >> 10, h = n & 1023;
  float wi = Wih[idx], wh = Whh[idx];
  int htile = h >> 3;
  int r  = ((h & 7) << 2) | g;         // local row 0..31
  int nt = r >> 4, lr2 = r & 15;
  int kb = k >> 5, lg2 = (k >> 3) & 3, e = k & 7;
  size_t dest = (size_t)htile * 32768 + (size_t)nt * 16384 + (size_t)kb * 512
              + (size_t)(lg2 * 16 + lr2) * 8 + e;
  Wsum_p[dest] = f2b(wi + wh);
  Whh_b[idx] = f2b(wh);
  if (idx < 4096) bias_sp[packrow((int)idx)] = bih[idx] + bhh[idx];
}

// bias0[n] (plain) = bih+bhh + sum_k W_ih[n,k]*go[0,k]
__global__ __launch_bounds__(256) void prep_b0(
    const float* __restrict__ Wih, const float* __restrict__ go,
    const float* __restrict__ bih, const float* __restrict__ bhh,
    float* __restrict__ bias0)
{
  __shared__ float red[4];
  int n = blockIdx.x, t = threadIdx.x;
  float acc = 0.f;
  for (int k = t; k < 1024; k += 256) acc += Wih[(size_t)n*1024 + k] * go[k];
  for (int off = 32; off > 0; off >>= 1) acc += __shfl_down(acc, off, 64);
  if ((t & 63) == 0) red[t >> 6] = acc;
  __syncthreads();
  if (t == 0) bias0[n] = bih[n] + bhh[n] + red[0] + red[1] + red[2] + red[3];
}

// ---- z projections (K=128, f32) ----
__global__ __launch_bounds__(256) void zproj(
    const float* __restrict__ z, const float* __restrict__ Wzh, const float* __restrict__ bzh,
    const float* __restrict__ Wzc, const float* __restrict__ bzc,
    float* __restrict__ zh_raw, float* __restrict__ zc_raw)
{
  int idx = blockIdx.x * 256 + threadIdx.x; // 256*1024
  int b = idx >> 10, c = idx & 1023;
  const float* zr = z + b * 128;
  const float* wh = Wzh + c * 128;
  const float* wc = Wzc + c * 128;
  float s1 = bzh[c], s2 = bzc[c];
  #pragma unroll 8
  for (int k = 0; k < 128; k++){ float zv = zr[k]; s1 += zv * wh[k]; s2 += zv * wc[k]; }
  zh_raw[idx] = s1; zc_raw[idx] = s2;
}

// ---- BN over batch: zh -> zh_b (bf16), zc -> c_f (f32) ----
__global__ __launch_bounds__(256) void bn_init(
    const float* __restrict__ zh_raw, const float* __restrict__ zc_raw,
    const float* __restrict__ g_h, const float* __restrict__ bt_h,
    const float* __restrict__ g_c, const float* __restrict__ bt_c,
    unsigned short* __restrict__ zh_b, float* __restrict__ c_f)
{
  __shared__ float red[4][4];
  int c = blockIdx.x, r = threadIdx.x;
  float v1 = zh_raw[r * 1024 + c];
  float v2 = zc_raw[r * 1024 + c];
  float s[4] = { v1, v1*v1, v2, v2*v2 };
  #pragma unroll
  for (int i = 0; i < 4; i++){
    float x = s[i];
    for (int off = 32; off > 0; off >>= 1) x += __shfl_down(x, off, 64);
    if ((r & 63) == 0) red[i][r >> 6] = x;
  }
  __syncthreads();
  float m1 = (red[0][0]+red[0][1]+red[0][2]+red[0][3]) * (1.f/256.f);
  float q1 = (red[1][0]+red[1][1]+red[1][2]+red[1][3]) * (1.f/256.f);
  float m2 = (red[2][0]+red[2][1]+red[2][2]+red[2][3]) * (1.f/256.f);
  float q2 = (red[3][0]+red[3][1]+red[3][2]+red[3][3]) * (1.f/256.f);
  float var1 = q1 - m1*m1; if (var1 < 0.f) var1 = 0.f;
  float var2 = q2 - m2*m2; if (var2 < 0.f) var2 = 0.f;
  float a1 = g_h[c] * rsqrtf(var1 + 1e-5f), be1 = bt_h[c] - m1*a1;
  float a2 = g_c[c] * rsqrtf(var2 + 1e-5f), be2 = bt_c[c] - m2*a2;
  zh_b[r * 1024 + c] = f2b(v1*a1 + be1);
  c_f[r * 1024 + c] = v2*a2 + be2;
}

// ---- MLP / step0 GEMM: out[M][N] = A[M][K] @ B[N][K]^T + bias; 64x128 tile ----
template<int K, int ACT, int OBF16>
__global__ __launch_bounds__(256) void gemm_bt2(
    const unsigned short* __restrict__ A, const unsigned short* __restrict__ B,
    const float* __restrict__ bias, void* __restrict__ outp, int N)
{
  const int tid = threadIdx.x;
  const int w = tid >> 6, l = tid & 63;
  const int lr = l & 15, lg = l >> 4;
  const int m0 = blockIdx.y * 64 + (w >> 1) * 32;
  const int n0 = blockIdx.x * 128 + (w & 1) * 64;
  f32x4 acc[2][4];
  #pragma unroll
  for (int i = 0; i < 2; i++)
    #pragma unroll
    for (int j = 0; j < 4; j++) acc[i][j] = (f32x4){0.f,0.f,0.f,0.f};

  const unsigned short* pa0 = A + (size_t)(m0 + lr) * K + lg * 8;
  const unsigned short* pa1 = pa0 + (size_t)16 * K;
  const unsigned short* pb0 = B + (size_t)(n0 + lr) * K + lg * 8;

  for (int kb = 0; kb < K; kb += 32){
    bf16x8 a0 = *(const bf16x8*)(pa0 + kb);
    bf16x8 a1 = *(const bf16x8*)(pa1 + kb);
    bf16x8 b0 = *(const bf16x8*)(pb0 + kb);
    bf16x8 b1 = *(const bf16x8*)(pb0 + (size_t)16 * K + kb);
    bf16x8 b2 = *(const bf16x8*)(pb0 + (size_t)32 * K + kb);
    bf16x8 b3 = *(const bf16x8*)(pb0 + (size_t)48 * K + kb);
    acc[0][0] = __builtin_amdgcn_mfma_f32_16x16x32_bf16(a0, b0, acc[0][0], 0, 0, 0);
    acc[0][1] = __builtin_amdgcn_mfma_f32_16x16x32_bf16(a0, b1, acc[0][1], 0, 0, 0);
    acc[0][2] = __builtin_amdgcn_mfma_f32_16x16x32_bf16(a0, b2, acc[0][2], 0, 0, 0);
    acc[0][3] = __builtin_amdgcn_mfma_f32_16x16x32_bf16(a0, b3, acc[0][3], 0, 0, 0);
    acc[1][0] = __builtin_amdgcn_mfma_f32_16x16x32_bf16(a1, b0, acc[1][0], 0, 0, 0);
    acc[1][1] = __builtin_amdgcn_mfma_f32_16x16x32_bf16(a1, b1, acc[1][1], 0, 0, 0);
    acc[1][2] = __builtin_amdgcn_mfma_f32_16x16x32_bf16(a1, b2, acc[1][2], 0, 0, 0);
    acc[1][3] = __builtin_amdgcn_mfma_f32_16x16x32_bf16(a1, b3, acc[1][3], 0, 0, 0);
  }

  #pragma unroll
  for (int mi = 0; mi < 2; mi++)
    #pragma unroll
    for (int ni = 0; ni < 4; ni++){
      int col = n0 + ni * 16 + lr;
      float bs = bias[col];
      #pragma unroll
      for (int j = 0; j < 4; j++){
        int row = m0 + mi * 16 + lg * 4 + j;
        float v = acc[mi][ni][j] + bs;
        if (ACT) v = v > 0.f ? v : 0.01f * v;
        if (OBF16) ((unsigned short*)outp)[(size_t)row * N + col] = f2b(v);
        else       ((float*)outp)[(size_t)row * N + col] = v;
      }
    }
}

// ---- step-0 cell: gates0 -> c, h(0) into hbuf0 ----
__global__ __launch_bounds__(256) void lstm_cell0(
    const float* __restrict__ gates, float* __restrict__ c,
    unsigned short* __restrict__ hbuf0)
{
  int idx = blockIdx.x * 256 + threadIdx.x; // 256*1024
  int b = idx >> 10, h = idx & 1023;
  const float* g = gates + (size_t)b * 4096;
  float ig = g[h], fg = g[1024 + h], gg = g[2048 + h], og = g[3072 + h];
  float co = c[idx];
  float c2 = sigm(fg) * co + sigm(ig) * tanh_f(gg);
  float h2 = sigm(og) * tanh_f(c2);
  c[idx] = c2;
  hbuf0[idx] = f2b(h2);
}

// ---- persistent LSTM: steps 1..255. 256 blocks x 256 threads (all CUs).
// Block = (mhalf = blk>>7) x (htile = blk&127): rows [mhalf*128,+128), h-cols [htile*8,+8).
__global__ __launch_bounds__(256, 1) void lstm_persist(
    const unsigned short* __restrict__ Wp, const float* __restrict__ bias_sp,
    unsigned short* __restrict__ hbuf0, unsigned short* __restrict__ hbuf1,
    const float* __restrict__ c_init, unsigned short* __restrict__ ys,
    unsigned int* __restrict__ arr, unsigned int* __restrict__ flagv)
{
  __shared__ unsigned short Wl[32768];        // 64 KB fragment-order W image
  __shared__ unsigned short chunk[1024][20];  // 40 KB: [(local row)*8+hl][t&15] (+pad)
  const int tid = threadIdx.x;
  const int blk = blockIdx.x;
  const int mhalf = blk >> 7;
  const int htile = blk & 127;
  const int w = tid >> 6, l = tid & 63;
  const int lr = l & 15, lg = l >> 4;
  const int m0 = mhalf * 128;

  // stage W image (prebaked layout): contiguous copy
  {
    const bf16x8* src = (const bf16x8*)(Wp + (size_t)htile * 32768);
    bf16x8* dst = (bf16x8*)Wl;
    for (int i = tid; i < 4096; i += 256) dst[i] = src[i];
  }
  // preload t=0 h into chunk slot 0
  for (int i = tid; i < 1024; i += 256){
    int b = i >> 3, hl = i & 7;
    chunk[i][0] = hbuf0[(size_t)(m0 + b) * 1024 + htile * 8 + hl];
  }

  const int hw0 = lr >> 2;
  float bb[2];
  bb[0] = bias_sp[htile * 32 + lr];
  bb[1] = bias_sp[htile * 32 + 16 + lr];

  float creg[2][2][4];
  #pragma unroll
  for (int mi = 0; mi < 2; mi++)
    #pragma unroll
    for (int ni = 0; ni < 2; ni++)
      #pragma unroll
      for (int j = 0; j < 4; j++){
        int row = m0 + w * 32 + mi * 16 + lg * 4 + j;
        int h = htile * 8 + ni * 4 + hw0;
        creg[mi][ni][j] = c_init[(size_t)row * 1024 + h];
      }

  __syncthreads();

  const char* lwb = (const char*)Wl + l * 16;

  #pragma unroll 1
  for (int t = 1; t < 256; t++){
    const unsigned short* hin = (t & 1) ? hbuf0 : hbuf1;
    unsigned int* hout32 = (unsigned int*)((t & 1) ? hbuf1 : hbuf0);

    f32x4 acc[2][2];
    #pragma unroll
    for (int i = 0; i < 2; i++)
      #pragma unroll
      for (int j = 0; j < 2; j++) acc[i][j] = (f32x4){0.f,0.f,0.f,0.f};

    const unsigned short* pa0 = hin + (size_t)(m0 + w * 32 + lr) * 1024 + lg * 8;
    const unsigned short* pa1 = pa0 + 16 * 1024;

    #pragma unroll 8
    for (int kb = 0; kb < 32; kb++){
      bf16x8 a0 = *(const bf16x8*)(pa0 + kb * 32);
      bf16x8 a1 = *(const bf16x8*)(pa1 + kb * 32);
      bf16x8 b0 = *(const bf16x8*)(lwb + kb * 1024);
      bf16x8 b1 = *(const bf16x8*)(lwb + 32768 + kb * 1024);
      acc[0][0] = __builtin_amdgcn_mfma_f32_16x16x32_bf16(a0, b0, acc[0][0], 0, 0, 0);
      acc[0][1] = __builtin_amdgcn_mfma_f32_16x16x32_bf16(a0, b1, acc[0][1], 0, 0, 0);
      acc[1][0] = __builtin_amdgcn_mfma_f32_16x16x32_bf16(a1, b0, acc[1][0], 0, 0, 0);
      acc[1][1] = __builtin_amdgcn_mfma_f32_16x16x32_bf16(a1, b1, acc[1][1], 0, 0, 0);
    }

    // cell epilogue: reunite 4 gates across the 4 gate-lanes (lr&3)
    #pragma unroll
    for (int mi = 0; mi < 2; mi++)
      #pragma unroll
      for (int ni = 0; ni < 2; ni++)
        #pragma unroll
        for (int j = 0; j < 4; j++){
          float v = acc[mi][ni][j] + bb[ni];
          float va = v;
          float vb = __shfl_xor(v, 1);
          float vc = __shfl_xor(v, 2);
          float vd = __shfl_xor(vb, 2);
          bool s1 = (lr & 1), s2 = (lr & 2);
          float P1 = s2 ? vc : va, P2 = s2 ? vd : vb;
          float Q1 = s2 ? va : vc, Q2 = s2 ? vb : vd;
          float gi  = s1 ? P2 : P1;
          float gf  = s1 ? P1 : P2;
          float gg  = s1 ? Q2 : Q1;
          float go_ = s1 ? Q1 : Q2;
          float c2 = sigm(gf) * creg[mi][ni][j] + sigm(gi) * tanh_f(gg);
          float h2 = sigm(go_) * tanh_f(c2);
          creg[mi][ni][j] = c2;
          unsigned short hb = f2b(h2);
          int rl = w * 32 + mi * 16 + lg * 4 + j;     // local row 0..127
          int hl = ni * 4 + hw0;
          if ((lr & 3) == 0) chunk[rl * 8 + hl][t & 15] = hb;  // LDS (ys path)
          // coherent h-out: pair (hl even, odd) into one dword via lane lr^4
          unsigned int pv = (unsigned int)(unsigned short)__shfl_xor((int)hb, 4);
          if ((lr & 7) == 1){
            unsigned int val = (pv << 16) | (unsigned int)hb;
            atomicExch(&hout32[(m0 + rl) * 512 + htile * 4 + ni * 2 + (hw0 >> 1)], val);
          }
        }

    __syncthreads();   // drain: all atomicExch h-stores + chunk LDS writes committed
    if (t < 255 && tid == 0)
      __hip_atomic_fetch_add(&arr[blk * 32], 1u, __ATOMIC_RELAXED, __HIP_MEMORY_SCOPE_AGENT);

    // dump 16-step chunk to ys — overlapped with barrier resolution
    if ((t & 15) == 15){
      int t0 = t - 15;
      for (int r = tid; r < 1024; r += 256){
        int b = r >> 3, hl = r & 7;
        uint2 p0 = *(const uint2*)&chunk[r][0];
        uint2 p1 = *(const uint2*)&chunk[r][4];
        uint2 p2 = *(const uint2*)&chunk[r][8];
        uint2 p3 = *(const uint2*)&chunk[r][12];
        size_t o = ((size_t)(m0 + b) * 1024 + htile * 8 + hl) * 256 + t0;
        *(uint4*)&ys[o]     = (uint4){p0.x, p0.y, p1.x, p1.y};
        *(uint4*)&ys[o + 8] = (uint4){p2.x, p2.y, p3.x, p3.y};
      }
    }

    if (t < 255){
      if (blk == 0){
        // 256 threads poll 256 private arrival lines in parallel
        int spin = 0;
        while (__hip_atomic_fetch_add(&arr[tid * 32], 0u, __ATOMIC_RELAXED,
                                      __HIP_MEMORY_SCOPE_AGENT) < (unsigned)t
               && spin < (1 << 16)) ++spin;
        __syncthreads();  // all 256 arrivals observed
        if (tid >= 1)
          __hip_atomic_fetch_add(&flagv[tid * 32], 1u, __ATOMIC_RELAXED,
                                 __HIP_MEMORY_SCOPE_AGENT);
      } else {
        if (tid == 0){
          int spin = 0;
          while (__hip_atomic_fetch_add(&flagv[blk * 32], 0u, __ATOMIC_RELAXED,
                                        __HIP_MEMORY_SCOPE_AGENT) < (unsigned)t
                 && spin < (1 << 16)) ++spin;
        }
      }
      if (tid == 0) __builtin_amdgcn_fence(__ATOMIC_ACQUIRE, "agent"); // inv stale hin
      __syncthreads();
    }
  }
}

// ---- column stats (sum, sumsq), stage 1 ----
template<int C>
__global__ __launch_bounds__(256) void stats1(
    const unsigned short* __restrict__ X, float* __restrict__ psum, float* __restrict__ psq)
{
  int col = blockIdx.x * 256 + threadIdx.x;
  int r0 = blockIdx.y * 256;
  float s = 0.f, q = 0.f;
  for (int r = r0; r < r0 + 256; r++){
    float v = b2f(X[(size_t)r * C + col]);
    s += v; q += v * v;
  }
  psum[(size_t)blockIdx.y * C + col] = s;
  psq [(size_t)blockIdx.y * C + col] = q;
}

__global__ __launch_bounds__(256) void stats2(
    const float* __restrict__ psum, const float* __restrict__ psq,
    const float* __restrict__ g, const float* __restrict__ b,
    float* __restrict__ alpha, float* __restrict__ beta, int C)
{
  int c = blockIdx.x * 256 + threadIdx.x;
  if (c >= C) return;
  float s = 0.f, q = 0.f;
  for (int i = 0; i < 256; i++){ s += psum[(size_t)i * C + c]; q += psq[(size_t)i * C + c]; }
  float m = s * (1.f / 65536.f);
  float var = q * (1.f / 65536.f) - m * m; if (var < 0.f) var = 0.f;
  float a = g[c] * rsqrtf(var + 1e-5f);
  alpha[c] = a; beta[c] = b[c] - m * a;
}

// ---- fold BN into weights ----
template<int K>
__global__ __launch_bounds__(256) void foldk(
    const float* __restrict__ W, const float* __restrict__ bias,
    const float* __restrict__ alpha, const float* __restrict__ beta,
    unsigned short* __restrict__ Wb, float* __restrict__ bp, int rows)
{
  __shared__ float red[4];
  int o = blockIdx.x, t = threadIdx.x;
  float acc = 0.f;
  if (o < rows){
    for (int j = t; j < K; j += 256){
      float wv = W[(size_t)o * K + j];
      acc += beta[j] * wv;
      Wb[(size_t)o * K + j] = f2b(wv * alpha[j]);
    }
  } else {
    for (int j = t; j < K; j += 256) Wb[(size_t)o * K + j] = 0;
  }
  for (int off = 32; off > 0; off >>= 1) acc += __shfl_down(acc, off, 64);
  if ((t & 63) == 0) red[t >> 6] = acc;
  __syncthreads();
  if (t == 0) bp[o] = (o < rows ? bias[o] : 0.f) + red[0] + red[1] + red[2] + red[3];
}

// ---- final softmax with raw-reshape index mixing ----
__global__ __launch_bounds__(256) void softmax_k(
    const unsigned short* __restrict__ o3p, float* __restrict__ out)
{
  __shared__ unsigned short tile[25600];
  int b = blockIdx.x, t = threadIdx.x;
  const unsigned short* src = o3p + (size_t)b * 256 * 128;
  for (int i = t; i < 25600; i += 256){
    int rr = i / 100, nc = i - rr * 100;
    tile[i] = src[rr * 128 + nc];
  }
  __syncthreads();
  int v = t;
  float mx = -1e30f;
  for (int u = 0; u < 100; u++) mx = fmaxf(mx, b2f(tile[u * 256 + v]));
  float s = 0.f;
  for (int u = 0; u < 100; u++) s += __expf(b2f(tile[u * 256 + v]) - mx);
  float inv = 1.f / s;
  float* dst = out + (size_t)b * 25600;
  for (int u = 0; u < 100; u++)
    dst[u * 256 + v] = __expf(b2f(tile[u * 256 + v]) - mx) * inv;
}

extern "C" void kernel_launch(void* const* d_in, const int* in_sizes, int n_in,
                              void* d_out, int out_size, void* d_ws, size_t ws_size,
                              hipStream_t stream)
{
  (void)in_sizes; (void)n_in;
  const float* z     = (const float*)d_in[0];
  const float* Wzh   = (const float*)d_in[1];
  const float* bzh   = (const float*)d_in[2];
  const float* Wzc   = (const float*)d_in[3];
  const float* bzc   = (const float*)d_in[4];
  const float* g_bnzh= (const float*)d_in[5];
  const float* b_bnzh= (const float*)d_in[6];
  const float* g_bnzc= (const float*)d_in[7];
  const float* b_bnzc= (const float*)d_in[8];
  const float* Wih   = (const float*)d_in[9];
  const float* bih   = (const float*)d_in[10];
  const float* Whh   = (const float*)d_in[11];
  const float* bhh   = (const float*)d_in[12];
  const float* g_bn0 = (const float*)d_in[13];
  const float* b_bn0 = (const float*)d_in[14];
  const float* W1    = (const float*)d_in[15];
  const float* b1    = (const float*)d_in[16];
  const float* g_bn1 = (const float*)d_in[17];
  const float* b_bn1 = (const float*)d_in[18];
  const float* W2    = (const float*)d_in[19];
  const float* b2    = (const float*)d_in[20];
  const float* g_bn2 = (const float*)d_in[21];
  const float* b_bn2 = (const float*)d_in[22];
  const float* W3    = (const float*)d_in[23];
  const float* b3    = (const float*)d_in[24];
  const float* go    = (const float*)d_in[25];

  char* base = (char*)d_ws;
  size_t off = 0;
  auto alloc = [&](size_t bytes)->char*{
    char* p = base + off;
    off = (off + bytes + 255) & ~(size_t)255;
    return p;
  };
  const size_t MB = 1024 * 1024;

  unsigned short* ys = (unsigned short*)alloc(128 * MB);  // [b*1024+h][256] bf16
  unsigned short* o1 = (unsigned short*)alloc(64 * MB);   // [65536][512] bf16
  char* zone = alloc(32 * MB);                            // dead after LSTM; o2 overlays
  unsigned short* Wsum_p = (unsigned short*)(zone);            // 8 MB
  unsigned short* Whh_b  = (unsigned short*)(zone + 8 * MB);   // 8 MB
  float*          gates0 = (float*)(zone + 16 * MB);           // 4 MB
  // persistent-small region
  float* zh_raw = (float*)alloc(1 * MB);
  float* zc_raw = (float*)alloc(1 * MB);
  float* bias_sp = (float*)alloc(16384);
  float* bias0   = (float*)alloc(16384);
  unsigned short* zh_b  = (unsigned short*)alloc((size_t)256 * 1024 * 2);
  unsigned short* hbuf0 = (unsigned short*)alloc((size_t)256 * 1024 * 2);
  unsigned short* hbuf1 = (unsigned short*)alloc((size_t)256 * 1024 * 2);
  float* c_f    = (float*)alloc((size_t)256 * 1024 * 4);
  float* psum   = (float*)alloc(1 * MB);
  float* psq    = (float*)alloc(1 * MB);
  float* alpha0 = (float*)alloc(4096); float* beta0 = (float*)alloc(4096);
  float* alpha1 = (float*)alloc(4096); float* beta1 = (float*)alloc(4096);
  float* alpha2 = (float*)alloc(4096); float* beta2 = (float*)alloc(4096);
  unsigned short* W1b = (unsigned short*)alloc((size_t)512 * 1024 * 2);
  unsigned short* W2b = (unsigned short*)alloc((size_t)256 * 512 * 2);
  unsigned short* W3b = (unsigned short*)alloc((size_t)128 * 256 * 2);
  float* b1p = (float*)alloc(4096);
  float* b2p = (float*)alloc(4096);
  float* b3p = (float*)alloc(4096);
  unsigned int* arr   = (unsigned int*)alloc(32768);   // 256 arrival counters, 128B stride
  unsigned int* flagv = (unsigned int*)alloc(32768);   // 256 flags, 128B stride
  unsigned short* o2  = (unsigned short*)zone;  // 32 MB overlays dead zone
  unsigned short* o3p = o1;                     // 16 MB overlays dead o1

  if (off > ws_size){
    zerofill<<<(out_size + 255) / 256, 256, 0, stream>>>((float*)d_out, out_size);
    return;
  }

  zerofill<<<64, 256, 0, stream>>>((float*)arr, 16384);
  prep_w<<<16384, 256, 0, stream>>>(Wih, Whh, bih, bhh, Wsum_p, Whh_b, bias_sp);
  prep_b0<<<4096, 256, 0, stream>>>(Wih, go, bih, bhh, bias0);
  zproj<<<1024, 256, 0, stream>>>(z, Wzh, bzh, Wzc, bzc, zh_raw, zc_raw);
  bn_init<<<1024, 256, 0, stream>>>(zh_raw, zc_raw, g_bnzh, b_bnzh, g_bnzc, b_bnzc, zh_b, c_f);

  // step 0: gates0 = zh @ Whh^T + bias0(go-term folded); then cell
  gemm_bt2<1024, 0, 0><<<dim3(32, 4), 256, 0, stream>>>(zh_b, Whh_b, bias0, gates0, 4096);
  lstm_cell0<<<1024, 256, 0, stream>>>(gates0, c_f, hbuf0);

  // steps 1..255 in one persistent kernel (all 256 CUs)
  lstm_persist<<<NBLK, 256, 0, stream>>>(Wsum_p, bias_sp, hbuf0, hbuf1, c_f, ys, arr, flagv);

  stats1<1024><<<dim3(4, 256), 256, 0, stream>>>(ys, psum, psq);
  stats2<<<4, 256, 0, stream>>>(psum, psq, g_bn0, b_bn0, alpha0, beta0, 1024);
  foldk<1024><<<512, 256, 0, stream>>>(W1, b1, alpha0, beta0, W1b, b1p, 512);
  gemm_bt2<1024, 1, 1><<<dim3(4, 1024), 256, 0, stream>>>(ys, W1b, b1p, o1, 512);

  stats1<512><<<dim3(2, 256), 256, 0, stream>>>(o1, psum, psq);
  stats2<<<2, 256, 0, stream>>>(psum, psq, g_bn1, b_bn1, alpha1, beta1, 512);
  foldk<512><<<256, 256, 0, stream>>>(W2, b2, alpha1, beta1, W2b, b2p, 256);
  gemm_bt2<512, 1, 1><<<dim3(2, 1024), 256, 0, stream>>>(o1, W2b, b2p, o2, 256);

  stats1<256><<<dim3(1, 256), 256, 0, stream>>>(o2, psum, psq);
  stats2<<<1, 256, 0, stream>>>(psum, psq, g_bn2, b_bn2, alpha2, beta2, 256);
  foldk<256><<<128, 256, 0, stream>>>(W3, b3, alpha2, beta2, W3b, b3p, 100);
  gemm_bt2<256, 0, 1><<<dim3(1, 1024), 256, 0, stream>>>(o2, W3b, b3p, o3p, 128);

  softmax_k<<<256, 256, 0, stream>>>(o3p, (float*)d_out);
}

// Round 10
// 4166.409 us; speedup vs baseline: 4.4058x; 1.2454x over previous
//
#include <hip/hip_runtime.h>
#include <hip/hip_bf16.h>

typedef __attribute__((ext_vector_type(8))) short bf16x8;
typedef __attribute__((ext_vector_type(4))) float f32x4;

#define NBLK 256   // 2 M-halves x 128 h-tiles

__device__ inline unsigned short f2b(float x){
  union { float f; unsigned int u; } v; v.f = x;
  unsigned int u = v.u;
  return (unsigned short)((u + 0x7FFFu + ((u >> 16) & 1u)) >> 16);
}
__device__ inline float b2f(unsigned short h){
  union { unsigned int u; float f; } v; v.u = ((unsigned int)h) << 16; return v.f;
}
__device__ inline float sigm(float x){ return 1.f / (1.f + __expf(-x)); }
__device__ inline float tanh_f(float x){ float e2 = __expf(2.f * x); return 1.f - 2.f / (e2 + 1.f); }

__global__ __launch_bounds__(256) void zerofill(float* __restrict__ p, int n){
  int i = blockIdx.x * 256 + threadIdx.x;
  if (i < n) p[i] = 0.f;
}

// packed row for gate-row n = g*1024 + h:  htile = h>>3, local = (h&7)*4 + g
__device__ inline int packrow(int n){
  int g = n >> 10, h = n & 1023;
  return (h >> 3) * 32 + (h & 7) * 4 + g;
}

// ---- prep: Wsum as per-htile LDS images (MFMA fragment order), Whh plain bf16, biases ----
__global__ __launch_bounds__(256) void prep_w(
    const float* __restrict__ Wih, const float* __restrict__ Whh,
    const float* __restrict__ bih, const float* __restrict__ bhh,
    unsigned short* __restrict__ Wsum_p, unsigned short* __restrict__ Whh_b,
    float* __restrict__ bias_sp)
{
  size_t idx = (size_t)blockIdx.x * 256 + threadIdx.x; // 4096*1024
  int n = (int)(idx >> 10), k = (int)(idx & 1023);
  int g = n >> 10, h = n & 1023;
  float wi = Wih[idx], wh = Whh[idx];
  int htile = h >> 3;
  int r  = ((h & 7) << 2) | g;         // local row 0..31
  int nt = r >> 4, lr2 = r & 15;
  int kb = k >> 5, lg2 = (k >> 3) & 3, e = k & 7;
  size_t dest = (size_t)htile * 32768 + (size_t)nt * 16384 + (size_t)kb * 512
              + (size_t)(lg2 * 16 + lr2) * 8 + e;
  Wsum_p[dest] = f2b(wi + wh);
  Whh_b[idx] = f2b(wh);
  if (idx < 4096) bias_sp[packrow((int)idx)] = bih[idx] + bhh[idx];
}

// bias0[n] (plain) = bih+bhh + sum_k W_ih[n,k]*go[0,k]
__global__ __launch_bounds__(256) void prep_b0(
    const float* __restrict__ Wih, const float* __restrict__ go,
    const float* __restrict__ bih, const float* __restrict__ bhh,
    float* __restrict__ bias0)
{
  __shared__ float red[4];
  int n = blockIdx.x, t = threadIdx.x;
  float acc = 0.f;
  for (int k = t; k < 1024; k += 256) acc += Wih[(size_t)n*1024 + k] * go[k];
  for (int off = 32; off > 0; off >>= 1) acc += __shfl_down(acc, off, 64);
  if ((t & 63) == 0) red[t >> 6] = acc;
  __syncthreads();
  if (t == 0) bias0[n] = bih[n] + bhh[n] + red[0] + red[1] + red[2] + red[3];
}

// ---- z projections (K=128, f32) ----
__global__ __launch_bounds__(256) void zproj(
    const float* __restrict__ z, const float* __restrict__ Wzh, const float* __restrict__ bzh,
    const float* __restrict__ Wzc, const float* __restrict__ bzc,
    float* __restrict__ zh_raw, float* __restrict__ zc_raw)
{
  int idx = blockIdx.x * 256 + threadIdx.x; // 256*1024
  int b = idx >> 10, c = idx & 1023;
  const float* zr = z + b * 128;
  const float* wh = Wzh + c * 128;
  const float* wc = Wzc + c * 128;
  float s1 = bzh[c], s2 = bzc[c];
  #pragma unroll 8
  for (int k = 0; k < 128; k++){ float zv = zr[k]; s1 += zv * wh[k]; s2 += zv * wc[k]; }
  zh_raw[idx] = s1; zc_raw[idx] = s2;
}

// ---- BN over batch: zh -> zh_b (bf16), zc -> c_f (f32) ----
__global__ __launch_bounds__(256) void bn_init(
    const float* __restrict__ zh_raw, const float* __restrict__ zc_raw,
    const float* __restrict__ g_h, const float* __restrict__ bt_h,
    const float* __restrict__ g_c, const float* __restrict__ bt_c,
    unsigned short* __restrict__ zh_b, float* __restrict__ c_f)
{
  __shared__ float red[4][4];
  int c = blockIdx.x, r = threadIdx.x;
  float v1 = zh_raw[r * 1024 + c];
  float v2 = zc_raw[r * 1024 + c];
  float s[4] = { v1, v1*v1, v2, v2*v2 };
  #pragma unroll
  for (int i = 0; i < 4; i++){
    float x = s[i];
    for (int off = 32; off > 0; off >>= 1) x += __shfl_down(x, off, 64);
    if ((r & 63) == 0) red[i][r >> 6] = x;
  }
  __syncthreads();
  float m1 = (red[0][0]+red[0][1]+red[0][2]+red[0][3]) * (1.f/256.f);
  float q1 = (red[1][0]+red[1][1]+red[1][2]+red[1][3]) * (1.f/256.f);
  float m2 = (red[2][0]+red[2][1]+red[2][2]+red[2][3]) * (1.f/256.f);
  float q2 = (red[3][0]+red[3][1]+red[3][2]+red[3][3]) * (1.f/256.f);
  float var1 = q1 - m1*m1; if (var1 < 0.f) var1 = 0.f;
  float var2 = q2 - m2*m2; if (var2 < 0.f) var2 = 0.f;
  float a1 = g_h[c] * rsqrtf(var1 + 1e-5f), be1 = bt_h[c] - m1*a1;
  float a2 = g_c[c] * rsqrtf(var2 + 1e-5f), be2 = bt_c[c] - m2*a2;
  zh_b[r * 1024 + c] = f2b(v1*a1 + be1);
  c_f[r * 1024 + c] = v2*a2 + be2;
}

// ---- MLP / step0 GEMM: out[M][N] = A[M][K] @ B[N][K]^T + bias; 64x128 tile ----
template<int K, int ACT, int OBF16>
__global__ __launch_bounds__(256) void gemm_bt2(
    const unsigned short* __restrict__ A, const unsigned short* __restrict__ B,
    const float* __restrict__ bias, void* __restrict__ outp, int N)
{
  const int tid = threadIdx.x;
  const int w = tid >> 6, l = tid & 63;
  const int lr = l & 15, lg = l >> 4;
  const int m0 = blockIdx.y * 64 + (w >> 1) * 32;
  const int n0 = blockIdx.x * 128 + (w & 1) * 64;
  f32x4 acc[2][4];
  #pragma unroll
  for (int i = 0; i < 2; i++)
    #pragma unroll
    for (int j = 0; j < 4; j++) acc[i][j] = (f32x4){0.f,0.f,0.f,0.f};

  const unsigned short* pa0 = A + (size_t)(m0 + lr) * K + lg * 8;
  const unsigned short* pa1 = pa0 + (size_t)16 * K;
  const unsigned short* pb0 = B + (size_t)(n0 + lr) * K + lg * 8;

  for (int kb = 0; kb < K; kb += 32){
    bf16x8 a0 = *(const bf16x8*)(pa0 + kb);
    bf16x8 a1 = *(const bf16x8*)(pa1 + kb);
    bf16x8 b0 = *(const bf16x8*)(pb0 + kb);
    bf16x8 b1 = *(const bf16x8*)(pb0 + (size_t)16 * K + kb);
    bf16x8 b2 = *(const bf16x8*)(pb0 + (size_t)32 * K + kb);
    bf16x8 b3 = *(const bf16x8*)(pb0 + (size_t)48 * K + kb);
    acc[0][0] = __builtin_amdgcn_mfma_f32_16x16x32_bf16(a0, b0, acc[0][0], 0, 0, 0);
    acc[0][1] = __builtin_amdgcn_mfma_f32_16x16x32_bf16(a0, b1, acc[0][1], 0, 0, 0);
    acc[0][2] = __builtin_amdgcn_mfma_f32_16x16x32_bf16(a0, b2, acc[0][2], 0, 0, 0);
    acc[0][3] = __builtin_amdgcn_mfma_f32_16x16x32_bf16(a0, b3, acc[0][3], 0, 0, 0);
    acc[1][0] = __builtin_amdgcn_mfma_f32_16x16x32_bf16(a1, b0, acc[1][0], 0, 0, 0);
    acc[1][1] = __builtin_amdgcn_mfma_f32_16x16x32_bf16(a1, b1, acc[1][1], 0, 0, 0);
    acc[1][2] = __builtin_amdgcn_mfma_f32_16x16x32_bf16(a1, b2, acc[1][2], 0, 0, 0);
    acc[1][3] = __builtin_amdgcn_mfma_f32_16x16x32_bf16(a1, b3, acc[1][3], 0, 0, 0);
  }

  #pragma unroll
  for (int mi = 0; mi < 2; mi++)
    #pragma unroll
    for (int ni = 0; ni < 4; ni++){
      int col = n0 + ni * 16 + lr;
      float bs = bias[col];
      #pragma unroll
      for (int j = 0; j < 4; j++){
        int row = m0 + mi * 16 + lg * 4 + j;
        float v = acc[mi][ni][j] + bs;
        if (ACT) v = v > 0.f ? v : 0.01f * v;
        if (OBF16) ((unsigned short*)outp)[(size_t)row * N + col] = f2b(v);
        else       ((float*)outp)[(size_t)row * N + col] = v;
      }
    }
}

// ---- step-0 cell: gates0 -> c, h(0) into hbuf0 ----
__global__ __launch_bounds__(256) void lstm_cell0(
    const float* __restrict__ gates, float* __restrict__ c,
    unsigned short* __restrict__ hbuf0)
{
  int idx = blockIdx.x * 256 + threadIdx.x; // 256*1024
  int b = idx >> 10, h = idx & 1023;
  const float* g = gates + (size_t)b * 4096;
  float ig = g[h], fg = g[1024 + h], gg = g[2048 + h], og = g[3072 + h];
  float co = c[idx];
  float c2 = sigm(fg) * co + sigm(ig) * tanh_f(gg);
  float h2 = sigm(og) * tanh_f(c2);
  c[idx] = c2;
  hbuf0[idx] = f2b(h2);
}

// ---- persistent LSTM: steps 1..255. 256 blocks x 512 threads (8 waves/CU).
// Block = (mhalf = blk>>7) x (htile = blk&127): rows [mhalf*128,+128), h-cols [htile*8,+8).
// Wave w owns rows [m0 + w*16, +16). All-to-all barrier: every block polls all arrival lines.
__global__ __launch_bounds__(512, 1) void lstm_persist(
    const unsigned short* __restrict__ Wp, const float* __restrict__ bias_sp,
    unsigned short* __restrict__ hbuf0, unsigned short* __restrict__ hbuf1,
    const float* __restrict__ c_init, unsigned short* __restrict__ ys,
    unsigned int* __restrict__ arr)
{
  __shared__ unsigned short Wl[32768];        // 64 KB fragment-order W image
  __shared__ unsigned short chunk[1024][20];  // 40 KB: [(local row)*8+hl][t&15] (+pad)
  const int tid = threadIdx.x;
  const int blk = blockIdx.x;
  const int mhalf = blk >> 7;
  const int htile = blk & 127;
  const int w = tid >> 6, l = tid & 63;   // w 0..7
  const int lr = l & 15, lg = l >> 4;
  const int m0 = mhalf * 128;

  // stage W image (prebaked layout): contiguous copy
  {
    const bf16x8* src = (const bf16x8*)(Wp + (size_t)htile * 32768);
    bf16x8* dst = (bf16x8*)Wl;
    for (int i = tid; i < 4096; i += 512) dst[i] = src[i];
  }
  // preload t=0 h into chunk slot 0
  for (int i = tid; i < 1024; i += 512){
    int b = i >> 3, hl = i & 7;
    chunk[i][0] = hbuf0[(size_t)(m0 + b) * 1024 + htile * 8 + hl];
  }

  const int hw0 = lr >> 2;
  float bb[2];
  bb[0] = bias_sp[htile * 32 + lr];
  bb[1] = bias_sp[htile * 32 + 16 + lr];

  float creg[2][4];
  #pragma unroll
  for (int ni = 0; ni < 2; ni++)
    #pragma unroll
    for (int j = 0; j < 4; j++){
      int row = m0 + w * 16 + lg * 4 + j;
      int h = htile * 8 + ni * 4 + hw0;
      creg[ni][j] = c_init[(size_t)row * 1024 + h];
    }

  __syncthreads();

  const char* lwb = (const char*)Wl + l * 16;

  #pragma unroll 1
  for (int t = 1; t < 256; t++){
    const unsigned short* hin = (t & 1) ? hbuf0 : hbuf1;
    unsigned int* hout32 = (unsigned int*)((t & 1) ? hbuf1 : hbuf0);

    f32x4 acc[2];
    acc[0] = (f32x4){0.f,0.f,0.f,0.f};
    acc[1] = (f32x4){0.f,0.f,0.f,0.f};

    const unsigned short* pa0 = hin + (size_t)(m0 + w * 16 + lr) * 1024 + lg * 8;

    #pragma unroll 8
    for (int kb = 0; kb < 32; kb++){
      bf16x8 a0 = *(const bf16x8*)(pa0 + kb * 32);
      bf16x8 b0 = *(const bf16x8*)(lwb + kb * 1024);
      bf16x8 b1 = *(const bf16x8*)(lwb + 32768 + kb * 1024);
      acc[0] = __builtin_amdgcn_mfma_f32_16x16x32_bf16(a0, b0, acc[0], 0, 0, 0);
      acc[1] = __builtin_amdgcn_mfma_f32_16x16x32_bf16(a0, b1, acc[1], 0, 0, 0);
    }

    // cell epilogue: reunite 4 gates across the 4 gate-lanes (lr&3)
    #pragma unroll
    for (int ni = 0; ni < 2; ni++)
      #pragma unroll
      for (int j = 0; j < 4; j++){
        float v = acc[ni][j] + bb[ni];
        float va = v;
        float vb = __shfl_xor(v, 1);
        float vc = __shfl_xor(v, 2);
        float vd = __shfl_xor(vb, 2);
        bool s1 = (lr & 1), s2 = (lr & 2);
        float P1 = s2 ? vc : va, P2 = s2 ? vd : vb;
        float Q1 = s2 ? va : vc, Q2 = s2 ? vb : vd;
        float gi  = s1 ? P2 : P1;
        float gf  = s1 ? P1 : P2;
        float gg  = s1 ? Q2 : Q1;
        float go_ = s1 ? Q1 : Q2;
        float c2 = sigm(gf) * creg[ni][j] + sigm(gi) * tanh_f(gg);
        float h2 = sigm(go_) * tanh_f(c2);
        creg[ni][j] = c2;
        unsigned short hb = f2b(h2);
        int rl = w * 16 + lg * 4 + j;     // local row 0..127
        int hl = ni * 4 + hw0;
        if ((lr & 3) == 0) chunk[rl * 8 + hl][t & 15] = hb;  // LDS (ys path)
        // coherent h-out: pair (hl even, odd) into one dword via lane lr^4
        unsigned int pv = (unsigned int)(unsigned short)__shfl_xor((int)hb, 4);
        if ((lr & 7) == 1){
          unsigned int val = (pv << 16) | (unsigned int)hb;
          atomicExch(&hout32[(m0 + rl) * 512 + htile * 4 + ni * 2 + (hw0 >> 1)], val);
        }
      }

    __syncthreads();   // drain: all atomicExch h-stores + chunk LDS writes committed
    if (t < 255 && tid == 0)
      __hip_atomic_fetch_add(&arr[blk * 32], 1u, __ATOMIC_RELAXED, __HIP_MEMORY_SCOPE_AGENT);

    // dump 16-step chunk to ys — overlapped with barrier resolution
    if ((t & 15) == 15){
      int t0 = t - 15;
      for (int r = tid; r < 1024; r += 512){
        int b = r >> 3, hl = r & 7;
        uint2 p0 = *(const uint2*)&chunk[r][0];
        uint2 p1 = *(const uint2*)&chunk[r][4];
        uint2 p2 = *(const uint2*)&chunk[r][8];
        uint2 p3 = *(const uint2*)&chunk[r][12];
        size_t o = ((size_t)(m0 + b) * 1024 + htile * 8 + hl) * 256 + t0;
        *(uint4*)&ys[o]     = (uint4){p0.x, p0.y, p1.x, p1.y};
        *(uint4*)&ys[o + 8] = (uint4){p2.x, p2.y, p3.x, p3.y};
      }
    }

    if (t < 255){
      // all-to-all detection: 256 threads poll the 256 arrival lines in parallel
      if (tid < NBLK){
        int spin = 0;
        while (__hip_atomic_fetch_add(&arr[tid * 32], 0u, __ATOMIC_RELAXED,
                                      __HIP_MEMORY_SCOPE_AGENT) < (unsigned)t
               && spin < (1 << 16)) ++spin;
      }
      __syncthreads();  // all arrivals observed by this block
      if (tid == 0) __builtin_amdgcn_fence(__ATOMIC_ACQUIRE, "agent"); // inv stale hin
      __syncthreads();
    }
  }
}

// ---- column stats (sum, sumsq), stage 1 ----
template<int C>
__global__ __launch_bounds__(256) void stats1(
    const unsigned short* __restrict__ X, float* __restrict__ psum, float* __restrict__ psq)
{
  int col = blockIdx.x * 256 + threadIdx.x;
  int r0 = blockIdx.y * 256;
  float s = 0.f, q = 0.f;
  for (int r = r0; r < r0 + 256; r++){
    float v = b2f(X[(size_t)r * C + col]);
    s += v; q += v * v;
  }
  psum[(size_t)blockIdx.y * C + col] = s;
  psq [(size_t)blockIdx.y * C + col] = q;
}

__global__ __launch_bounds__(256) void stats2(
    const float* __restrict__ psum, const float* __restrict__ psq,
    const float* __restrict__ g, const float* __restrict__ b,
    float* __restrict__ alpha, float* __restrict__ beta, int C)
{
  int c = blockIdx.x * 256 + threadIdx.x;
  if (c >= C) return;
  float s = 0.f, q = 0.f;
  for (int i = 0; i < 256; i++){ s += psum[(size_t)i * C + c]; q += psq[(size_t)i * C + c]; }
  float m = s * (1.f / 65536.f);
  float var = q * (1.f / 65536.f) - m * m; if (var < 0.f) var = 0.f;
  float a = g[c] * rsqrtf(var + 1e-5f);
  alpha[c] = a; beta[c] = b[c] - m * a;
}

// ---- fold BN into weights ----
template<int K>
__global__ __launch_bounds__(256) void foldk(
    const float* __restrict__ W, const float* __restrict__ bias,
    const float* __restrict__ alpha, const float* __restrict__ beta,
    unsigned short* __restrict__ Wb, float* __restrict__ bp, int rows)
{
  __shared__ float red[4];
  int o = blockIdx.x, t = threadIdx.x;
  float acc = 0.f;
  if (o < rows){
    for (int j = t; j < K; j += 256){
      float wv = W[(size_t)o * K + j];
      acc += beta[j] * wv;
      Wb[(size_t)o * K + j] = f2b(wv * alpha[j]);
    }
  } else {
    for (int j = t; j < K; j += 256) Wb[(size_t)o * K + j] = 0;
  }
  for (int off = 32; off > 0; off >>= 1) acc += __shfl_down(acc, off, 64);
  if ((t & 63) == 0) red[t >> 6] = acc;
  __syncthreads();
  if (t == 0) bp[o] = (o < rows ? bias[o] : 0.f) + red[0] + red[1] + red[2] + red[3];
}

// ---- final softmax with raw-reshape index mixing ----
__global__ __launch_bounds__(256) void softmax_k(
    const unsigned short* __restrict__ o3p, float* __restrict__ out)
{
  __shared__ unsigned short tile[25600];
  int b = blockIdx.x, t = threadIdx.x;
  const unsigned short* src = o3p + (size_t)b * 256 * 128;
  for (int i = t; i < 25600; i += 256){
    int rr = i / 100, nc = i - rr * 100;
    tile[i] = src[rr * 128 + nc];
  }
  __syncthreads();
  int v = t;
  float mx = -1e30f;
  for (int u = 0; u < 100; u++) mx = fmaxf(mx, b2f(tile[u * 256 + v]));
  float s = 0.f;
  for (int u = 0; u < 100; u++) s += __expf(b2f(tile[u * 256 + v]) - mx);
  float inv = 1.f / s;
  float* dst = out + (size_t)b * 25600;
  for (int u = 0; u < 100; u++)
    dst[u * 256 + v] = __expf(b2f(tile[u * 256 + v]) - mx) * inv;
}

extern "C" void kernel_launch(void* const* d_in, const int* in_sizes, int n_in,
                              void* d_out, int out_size, void* d_ws, size_t ws_size,
                              hipStream_t stream)
{
  (void)in_sizes; (void)n_in;
  const float* z     = (const float*)d_in[0];
  const float* Wzh   = (const float*)d_in[1];
  const float* bzh   = (const float*)d_in[2];
  const float* Wzc   = (const float*)d_in[3];
  const float* bzc   = (const float*)d_in[4];
  const float* g_bnzh= (const float*)d_in[5];
  const float* b_bnzh= (const float*)d_in[6];
  const float* g_bnzc= (const float*)d_in[7];
  const float* b_bnzc= (const float*)d_in[8];
  const float* Wih   = (const float*)d_in[9];
  const float* bih   = (const float*)d_in[10];
  const float* Whh   = (const float*)d_in[11];
  const float* bhh   = (const float*)d_in[12];
  const float* g_bn0 = (const float*)d_in[13];
  const float* b_bn0 = (const float*)d_in[14];
  const float* W1    = (const float*)d_in[15];
  const float* b1    = (const float*)d_in[16];
  const float* g_bn1 = (const float*)d_in[17];
  const float* b_bn1 = (const float*)d_in[18];
  const float* W2    = (const float*)d_in[19];
  const float* b2    = (const float*)d_in[20];
  const float* g_bn2 = (const float*)d_in[21];
  const float* b_bn2 = (const float*)d_in[22];
  const float* W3    = (const float*)d_in[23];
  const float* b3    = (const float*)d_in[24];
  const float* go    = (const float*)d_in[25];

  char* base = (char*)d_ws;
  size_t off = 0;
  auto alloc = [&](size_t bytes)->char*{
    char* p = base + off;
    off = (off + bytes + 255) & ~(size_t)255;
    return p;
  };
  const size_t MB = 1024 * 1024;

  unsigned short* ys = (unsigned short*)alloc(128 * MB);  // [b*1024+h][256] bf16
  unsigned short* o1 = (unsigned short*)alloc(64 * MB);   // [65536][512] bf16
  char* zone = alloc(32 * MB);                            // dead after LSTM; o2 overlays
  unsigned short* Wsum_p = (unsigned short*)(zone);            // 8 MB
  unsigned short* Whh_b  = (unsigned short*)(zone + 8 * MB);   // 8 MB
  float*          gates0 = (float*)(zone + 16 * MB);           // 4 MB
  // persistent-small region
  float* zh_raw = (float*)alloc(1 * MB);
  float* zc_raw = (float*)alloc(1 * MB);
  float* bias_sp = (float*)alloc(16384);
  float* bias0   = (float*)alloc(16384);
  unsigned short* zh_b  = (unsigned short*)alloc((size_t)256 * 1024 * 2);
  unsigned short* hbuf0 = (unsigned short*)alloc((size_t)256 * 1024 * 2);
  unsigned short* hbuf1 = (unsigned short*)alloc((size_t)256 * 1024 * 2);
  float* c_f    = (float*)alloc((size_t)256 * 1024 * 4);
  float* psum   = (float*)alloc(1 * MB);
  float* psq    = (float*)alloc(1 * MB);
  float* alpha0 = (float*)alloc(4096); float* beta0 = (float*)alloc(4096);
  float* alpha1 = (float*)alloc(4096); float* beta1 = (float*)alloc(4096);
  float* alpha2 = (float*)alloc(4096); float* beta2 = (float*)alloc(4096);
  unsigned short* W1b = (unsigned short*)alloc((size_t)512 * 1024 * 2);
  unsigned short* W2b = (unsigned short*)alloc((size_t)256 * 512 * 2);
  unsigned short* W3b = (unsigned short*)alloc((size_t)128 * 256 * 2);
  float* b1p = (float*)alloc(4096);
  float* b2p = (float*)alloc(4096);
  float* b3p = (float*)alloc(4096);
  unsigned int* arr = (unsigned int*)alloc(32768);   // 256 arrival counters, 128B stride
  unsigned short* o2  = (unsigned short*)zone;  // 32 MB overlays dead zone
  unsigned short* o3p = o1;                     // 16 MB overlays dead o1

  if (off > ws_size){
    zerofill<<<(out_size + 255) / 256, 256, 0, stream>>>((float*)d_out, out_size);
    return;
  }

  zerofill<<<32, 256, 0, stream>>>((float*)arr, 8192);
  prep_w<<<16384, 256, 0, stream>>>(Wih, Whh, bih, bhh, Wsum_p, Whh_b, bias_sp);
  prep_b0<<<4096, 256, 0, stream>>>(Wih, go, bih, bhh, bias0);
  zproj<<<1024, 256, 0, stream>>>(z, Wzh, bzh, Wzc, bzc, zh_raw, zc_raw);
  bn_init<<<1024, 256, 0, stream>>>(zh_raw, zc_raw, g_bnzh, b_bnzh, g_bnzc, b_bnzc, zh_b, c_f);

  // step 0: gates0 = zh @ Whh^T + bias0(go-term folded); then cell
  gemm_bt2<1024, 0, 0><<<dim3(32, 4), 256, 0, stream>>>(zh_b, Whh_b, bias0, gates0, 4096);
  lstm_cell0<<<1024, 256, 0, stream>>>(gates0, c_f, hbuf0);

  // steps 1..255 in one persistent kernel (256 blocks x 512 threads, 8 waves/CU)
  lstm_persist<<<NBLK, 512, 0, stream>>>(Wsum_p, bias_sp, hbuf0, hbuf1, c_f, ys, arr);

  stats1<1024><<<dim3(4, 256), 256, 0, stream>>>(ys, psum, psq);
  stats2<<<4, 256, 0, stream>>>(psum, psq, g_bn0, b_bn0, alpha0, beta0, 1024);
  foldk<1024><<<512, 256, 0, stream>>>(W1, b1, alpha0, beta0, W1b, b1p, 512);
  gemm_bt2<1024, 1, 1><<<dim3(4, 1024), 256, 0, stream>>>(ys, W1b, b1p, o1, 512);

  stats1<512><<<dim3(2, 256), 256, 0, stream>>>(o1, psum, psq);
  stats2<<<2, 256, 0, stream>>>(psum, psq, g_bn1, b_bn1, alpha1, beta1, 512);
  foldk<512><<<256, 256, 0, stream>>>(W2, b2, alpha1, beta1, W2b, b2p, 256);
  gemm_bt2<512, 1, 1><<<dim3(2, 1024), 256, 0, stream>>>(o1, W2b, b2p, o2, 256);

  stats1<256><<<dim3(1, 256), 256, 0, stream>>>(o2, psum, psq);
  stats2<<<1, 256, 0, stream>>>(psum, psq, g_bn2, b_bn2, alpha2, beta2, 256);
  foldk<256><<<128, 256, 0, stream>>>(W3, b3, alpha2, beta2, W3b, b3p, 100);
  gemm_bt2<256, 0, 1><<<dim3(1, 1024), 256, 0, stream>>>(o2, W3b, b3p, o3p, 128);

  softmax_k<<<256, 256, 0, stream>>>(o3p, (float*)d_out);
}

// Round 12
// 3979.675 us; speedup vs baseline: 4.6125x; 1.0469x over previous
//
#include <hip/hip_runtime.h>
#include <hip/hip_bf16.h>

typedef __attribute__((ext_vector_type(8))) short bf16x8;
typedef __attribute__((ext_vector_type(4))) float f32x4;

#define NBLK 256   // 2 M-halves x 128 h-tiles

__device__ inline unsigned short f2b(float x){
  union { float f; unsigned int u; } v; v.f = x;
  unsigned int u = v.u;
  return (unsigned short)((u + 0x7FFFu + ((u >> 16) & 1u)) >> 16);
}
__device__ inline float b2f(unsigned short h){
  union { unsigned int u; float f; } v; v.u = ((unsigned int)h) << 16; return v.f;
}
__device__ inline float sigm(float x){ return 1.f / (1.f + __expf(-x)); }
__device__ inline float tanh_f(float x){ float e2 = __expf(2.f * x); return 1.f - 2.f / (e2 + 1.f); }

__global__ __launch_bounds__(256) void zerofill(float* __restrict__ p, int n){
  int i = blockIdx.x * 256 + threadIdx.x;
  if (i < n) p[i] = 0.f;
}

// packed row for gate-row n = g*1024 + h:  htile = h>>3, local = (h&7)*4 + g
__device__ inline int packrow(int n){
  int g = n >> 10, h = n & 1023;
  return (h >> 3) * 32 + (h & 7) * 4 + g;
}

// ---- prep: Wsum as per-htile LDS images (MFMA fragment order), Whh plain bf16, biases ----
__global__ __launch_bounds__(256) void prep_w(
    const float* __restrict__ Wih, const float* __restrict__ Whh,
    const float* __restrict__ bih, const float* __restrict__ bhh,
    unsigned short* __restrict__ Wsum_p, unsigned short* __restrict__ Whh_b,
    float* __restrict__ bias_sp)
{
  size_t idx = (size_t)blockIdx.x * 256 + threadIdx.x; // 4096*1024
  int n = (int)(idx >> 10), k = (int)(idx & 1023);
  int g = n >> 10, h = n & 1023;
  float wi = Wih[idx], wh = Whh[idx];
  int htile = h >> 3;
  int r  = ((h & 7) << 2) | g;         // local row 0..31
  int nt = r >> 4, lr2 = r & 15;
  int kb = k >> 5, lg2 = (k >> 3) & 3, e = k & 7;
  size_t dest = (size_t)htile * 32768 + (size_t)nt * 16384 + (size_t)kb * 512
              + (size_t)(lg2 * 16 + lr2) * 8 + e;
  Wsum_p[dest] = f2b(wi + wh);
  Whh_b[idx] = f2b(wh);
  if (idx < 4096) bias_sp[packrow((int)idx)] = bih[idx] + bhh[idx];
}

// bias0[n] (plain) = bih+bhh + sum_k W_ih[n,k]*go[0,k]
__global__ __launch_bounds__(256) void prep_b0(
    const float* __restrict__ Wih, const float* __restrict__ go,
    const float* __restrict__ bih, const float* __restrict__ bhh,
    float* __restrict__ bias0)
{
  __shared__ float red[4];
  int n = blockIdx.x, t = threadIdx.x;
  float acc = 0.f;
  for (int k = t; k < 1024; k += 256) acc += Wih[(size_t)n*1024 + k] * go[k];
  for (int off = 32; off > 0; off >>= 1) acc += __shfl_down(acc, off, 64);
  if ((t & 63) == 0) red[t >> 6] = acc;
  __syncthreads();
  if (t == 0) bias0[n] = bih[n] + bhh[n] + red[0] + red[1] + red[2] + red[3];
}

// ---- z projections (K=128, f32) ----
__global__ __launch_bounds__(256) void zproj(
    const float* __restrict__ z, const float* __restrict__ Wzh, const float* __restrict__ bzh,
    const float* __restrict__ Wzc, const float* __restrict__ bzc,
    float* __restrict__ zh_raw, float* __restrict__ zc_raw)
{
  int idx = blockIdx.x * 256 + threadIdx.x; // 256*1024
  int b = idx >> 10, c = idx & 1023;
  const float* zr = z + b * 128;
  const float* wh = Wzh + c * 128;
  const float* wc = Wzc + c * 128;
  float s1 = bzh[c], s2 = bzc[c];
  #pragma unroll 8
  for (int k = 0; k < 128; k++){ float zv = zr[k]; s1 += zv * wh[k]; s2 += zv * wc[k]; }
  zh_raw[idx] = s1; zc_raw[idx] = s2;
}

// ---- BN over batch: zh -> zh_b (bf16), zc -> c_f (f32) ----
__global__ __launch_bounds__(256) void bn_init(
    const float* __restrict__ zh_raw, const float* __restrict__ zc_raw,
    const float* __restrict__ g_h, const float* __restrict__ bt_h,
    const float* __restrict__ g_c, const float* __restrict__ bt_c,
    unsigned short* __restrict__ zh_b, float* __restrict__ c_f)
{
  __shared__ float red[4][4];
  int c = blockIdx.x, r = threadIdx.x;
  float v1 = zh_raw[r * 1024 + c];
  float v2 = zc_raw[r * 1024 + c];
  float s[4] = { v1, v1*v1, v2, v2*v2 };
  #pragma unroll
  for (int i = 0; i < 4; i++){
    float x = s[i];
    for (int off = 32; off > 0; off >>= 1) x += __shfl_down(x, off, 64);
    if ((r & 63) == 0) red[i][r >> 6] = x;
  }
  __syncthreads();
  float m1 = (red[0][0]+red[0][1]+red[0][2]+red[0][3]) * (1.f/256.f);
  float q1 = (red[1][0]+red[1][1]+red[1][2]+red[1][3]) * (1.f/256.f);
  float m2 = (red[2][0]+red[2][1]+red[2][2]+red[2][3]) * (1.f/256.f);
  float q2 = (red[3][0]+red[3][1]+red[3][2]+red[3][3]) * (1.f/256.f);
  float var1 = q1 - m1*m1; if (var1 < 0.f) var1 = 0.f;
  float var2 = q2 - m2*m2; if (var2 < 0.f) var2 = 0.f;
  float a1 = g_h[c] * rsqrtf(var1 + 1e-5f), be1 = bt_h[c] - m1*a1;
  float a2 = g_c[c] * rsqrtf(var2 + 1e-5f), be2 = bt_c[c] - m2*a2;
  zh_b[r * 1024 + c] = f2b(v1*a1 + be1);
  c_f[r * 1024 + c] = v2*a2 + be2;
}

// ---- MLP / step0 GEMM: out[M][N] = A[M][K] @ B[N][K]^T + bias; 64x128 tile ----
template<int K, int ACT, int OBF16>
__global__ __launch_bounds__(256) void gemm_bt2(
    const unsigned short* __restrict__ A, const unsigned short* __restrict__ B,
    const float* __restrict__ bias, void* __restrict__ outp, int N)
{
  const int tid = threadIdx.x;
  const int w = tid >> 6, l = tid & 63;
  const int lr = l & 15, lg = l >> 4;
  const int m0 = blockIdx.y * 64 + (w >> 1) * 32;
  const int n0 = blockIdx.x * 128 + (w & 1) * 64;
  f32x4 acc[2][4];
  #pragma unroll
  for (int i = 0; i < 2; i++)
    #pragma unroll
    for (int j = 0; j < 4; j++) acc[i][j] = (f32x4){0.f,0.f,0.f,0.f};

  const unsigned short* pa0 = A + (size_t)(m0 + lr) * K + lg * 8;
  const unsigned short* pa1 = pa0 + (size_t)16 * K;
  const unsigned short* pb0 = B + (size_t)(n0 + lr) * K + lg * 8;

  for (int kb = 0; kb < K; kb += 32){
    bf16x8 a0 = *(const bf16x8*)(pa0 + kb);
    bf16x8 a1 = *(const bf16x8*)(pa1 + kb);
    bf16x8 b0 = *(const bf16x8*)(pb0 + kb);
    bf16x8 b1 = *(const bf16x8*)(pb0 + (size_t)16 * K + kb);
    bf16x8 b2 = *(const bf16x8*)(pb0 + (size_t)32 * K + kb);
    bf16x8 b3 = *(const bf16x8*)(pb0 + (size_t)48 * K + kb);
    acc[0][0] = __builtin_amdgcn_mfma_f32_16x16x32_bf16(a0, b0, acc[0][0], 0, 0, 0);
    acc[0][1] = __builtin_amdgcn_mfma_f32_16x16x32_bf16(a0, b1, acc[0][1], 0, 0, 0);
    acc[0][2] = __builtin_amdgcn_mfma_f32_16x16x32_bf16(a0, b2, acc[0][2], 0, 0, 0);
    acc[0][3] = __builtin_amdgcn_mfma_f32_16x16x32_bf16(a0, b3, acc[0][3], 0, 0, 0);
    acc[1][0] = __builtin_amdgcn_mfma_f32_16x16x32_bf16(a1, b0, acc[1][0], 0, 0, 0);
    acc[1][1] = __builtin_amdgcn_mfma_f32_16x16x32_bf16(a1, b1, acc[1][1], 0, 0, 0);
    acc[1][2] = __builtin_amdgcn_mfma_f32_16x16x32_bf16(a1, b2, acc[1][2], 0, 0, 0);
    acc[1][3] = __builtin_amdgcn_mfma_f32_16x16x32_bf16(a1, b3, acc[1][3], 0, 0, 0);
  }

  #pragma unroll
  for (int mi = 0; mi < 2; mi++)
    #pragma unroll
    for (int ni = 0; ni < 4; ni++){
      int col = n0 + ni * 16 + lr;
      float bs = bias[col];
      #pragma unroll
      for (int j = 0; j < 4; j++){
        int row = m0 + mi * 16 + lg * 4 + j;
        float v = acc[mi][ni][j] + bs;
        if (ACT) v = v > 0.f ? v : 0.01f * v;
        if (OBF16) ((unsigned short*)outp)[(size_t)row * N + col] = f2b(v);
        else       ((float*)outp)[(size_t)row * N + col] = v;
      }
    }
}

// ---- step-0 cell: gates0 -> c, h(0) into hbuf0 ----
__global__ __launch_bounds__(256) void lstm_cell0(
    const float* __restrict__ gates, float* __restrict__ c,
    unsigned short* __restrict__ hbuf0)
{
  int idx = blockIdx.x * 256 + threadIdx.x; // 256*1024
  int b = idx >> 10, h = idx & 1023;
  const float* g = gates + (size_t)b * 4096;
  float ig = g[h], fg = g[1024 + h], gg = g[2048 + h], og = g[3072 + h];
  float co = c[idx];
  float c2 = sigm(fg) * co + sigm(ig) * tanh_f(gg);
  float h2 = sigm(og) * tanh_f(c2);
  c[idx] = c2;
  hbuf0[idx] = f2b(h2);
}

// ---- persistent LSTM: steps 1..255. 256 blocks x 512 threads (8 waves/CU).
// Block = (mhalf = blk>>7) x (htile = blk&127). The two halves are data-independent:
// each runs its own 128-block barrier (2 leader blocks/half, per-block release lines).
__global__ __launch_bounds__(512, 1) void lstm_persist(
    const unsigned short* __restrict__ Wp, const float* __restrict__ bias_sp,
    unsigned short* __restrict__ hbuf0, unsigned short* __restrict__ hbuf1,
    const float* __restrict__ c_init, unsigned short* __restrict__ ys,
    unsigned int* __restrict__ arr, unsigned int* __restrict__ rel)
{
  __shared__ unsigned short Wl[32768];        // 64 KB fragment-order W image
  __shared__ unsigned short chunk[1024][20];  // 40 KB: [(local row)*8+hl][t&15] (+pad)
  const int tid = threadIdx.x;
  const int blk = blockIdx.x;
  const int mhalf = blk >> 7;
  const int htile = blk & 127;
  const int w = tid >> 6, l = tid & 63;   // w 0..7
  const int lr = l & 15, lg = l >> 4;
  const int m0 = mhalf * 128;
  const int halfbase = mhalf << 7;
  const int lid = blk - halfbase;         // 0..127 within the half
  const bool leader = (lid < 2);

  // stage W image (prebaked layout): contiguous copy
  {
    const bf16x8* src = (const bf16x8*)(Wp + (size_t)htile * 32768);
    bf16x8* dst = (bf16x8*)Wl;
    for (int i = tid; i < 4096; i += 512) dst[i] = src[i];
  }
  // preload t=0 h into chunk slot 0
  for (int i = tid; i < 1024; i += 512){
    int b = i >> 3, hl = i & 7;
    chunk[i][0] = hbuf0[(size_t)(m0 + b) * 1024 + htile * 8 + hl];
  }

  const int hw0 = lr >> 2;
  float bb[2];
  bb[0] = bias_sp[htile * 32 + lr];
  bb[1] = bias_sp[htile * 32 + 16 + lr];

  float creg[2][4];
  #pragma unroll
  for (int ni = 0; ni < 2; ni++)
    #pragma unroll
    for (int j = 0; j < 4; j++){
      int row = m0 + w * 16 + lg * 4 + j;
      int h = htile * 8 + ni * 4 + hw0;
      creg[ni][j] = c_init[(size_t)row * 1024 + h];
    }

  __syncthreads();

  const char* lwb = (const char*)Wl + l * 16;

  #pragma unroll 1
  for (int t = 1; t < 256; t++){
    const unsigned short* hin = (t & 1) ? hbuf0 : hbuf1;
    unsigned int* hout32 = (unsigned int*)((t & 1) ? hbuf1 : hbuf0);

    f32x4 acc[2];
    acc[0] = (f32x4){0.f,0.f,0.f,0.f};
    acc[1] = (f32x4){0.f,0.f,0.f,0.f};

    const unsigned short* pa0 = hin + (size_t)(m0 + w * 16 + lr) * 1024 + lg * 8;

    #pragma unroll 8
    for (int kb = 0; kb < 32; kb++){
      bf16x8 a0 = *(const bf16x8*)(pa0 + kb * 32);
      bf16x8 b0 = *(const bf16x8*)(lwb + kb * 1024);
      bf16x8 b1 = *(const bf16x8*)(lwb + 32768 + kb * 1024);
      acc[0] = __builtin_amdgcn_mfma_f32_16x16x32_bf16(a0, b0, acc[0], 0, 0, 0);
      acc[1] = __builtin_amdgcn_mfma_f32_16x16x32_bf16(a0, b1, acc[1], 0, 0, 0);
    }

    // cell epilogue: reunite 4 gates across the 4 gate-lanes (lr&3)
    #pragma unroll
    for (int ni = 0; ni < 2; ni++)
      #pragma unroll
      for (int j = 0; j < 4; j++){
        float v = acc[ni][j] + bb[ni];
        float va = v;
        float vb = __shfl_xor(v, 1);
        float vc = __shfl_xor(v, 2);
        float vd = __shfl_xor(vb, 2);
        bool s1 = (lr & 1), s2 = (lr & 2);
        float P1 = s2 ? vc : va, P2 = s2 ? vd : vb;
        float Q1 = s2 ? va : vc, Q2 = s2 ? vb : vd;
        float gi  = s1 ? P2 : P1;
        float gf  = s1 ? P1 : P2;
        float gg  = s1 ? Q2 : Q1;
        float go_ = s1 ? Q1 : Q2;
        float c2 = sigm(gf) * creg[ni][j] + sigm(gi) * tanh_f(gg);
        float h2 = sigm(go_) * tanh_f(c2);
        creg[ni][j] = c2;
        unsigned short hb = f2b(h2);
        int rl = w * 16 + lg * 4 + j;     // local row 0..127
        int hl = ni * 4 + hw0;
        if ((lr & 3) == 0) chunk[rl * 8 + hl][t & 15] = hb;  // LDS (ys path)
        // coherent h-out: pair (hl even, odd) into one dword via lane lr^4
        unsigned int pv = (unsigned int)(unsigned short)__shfl_xor((int)hb, 4);
        if ((lr & 7) == 1){
          unsigned int val = (pv << 16) | (unsigned int)hb;
          atomicExch(&hout32[(m0 + rl) * 512 + htile * 4 + ni * 2 + (hw0 >> 1)], val);
        }
      }

    __syncthreads();   // drain: all atomicExch h-stores + chunk LDS writes committed
    if (t < 255 && tid == 0)
      __hip_atomic_fetch_add(&arr[blk * 32], 1u, __ATOMIC_RELAXED, __HIP_MEMORY_SCOPE_AGENT);

    // dump 16-step chunk to ys — overlapped with barrier resolution
    if ((t & 15) == 15){
      int t0 = t - 15;
      for (int r = tid; r < 1024; r += 512){
        int b = r >> 3, hl = r & 7;
        uint2 p0 = *(const uint2*)&chunk[r][0];
        uint2 p1 = *(const uint2*)&chunk[r][4];
        uint2 p2 = *(const uint2*)&chunk[r][8];
        uint2 p3 = *(const uint2*)&chunk[r][12];
        size_t o = ((size_t)(m0 + b) * 1024 + htile * 8 + hl) * 256 + t0;
        *(uint4*)&ys[o]     = (uint4){p0.x, p0.y, p1.x, p1.y};
        *(uint4*)&ys[o + 8] = (uint4){p2.x, p2.y, p3.x, p3.y};
      }
    }

    if (t < 255){
      if (leader){
        // leader: 128 threads poll this half's 128 arrival lines (2 pollers/line)
        if (tid < 128){
          int spin = 0;
          while (__hip_atomic_fetch_add(&arr[(halfbase + tid) * 32], 0u,
                                        __ATOMIC_RELAXED, __HIP_MEMORY_SCOPE_AGENT)
                     < (unsigned)t
                 && spin < (1 << 16)){
            __builtin_amdgcn_s_sleep(1);
            ++spin;
          }
        }
        __syncthreads();  // all 128 arrivals of this half observed
        // release my 64-block share (parallel RMWs, 1 writer per line)
        if (tid < 64)
          __hip_atomic_fetch_add(&rel[(halfbase + lid * 64 + tid) * 32], 1u,
                                 __ATOMIC_RELAXED, __HIP_MEMORY_SCOPE_AGENT);
      } else {
        // member: poll only my own release line (1 writer + 1 poller)
        if (tid == 0){
          int spin = 0;
          while (__hip_atomic_fetch_add(&rel[blk * 32], 0u,
                                        __ATOMIC_RELAXED, __HIP_MEMORY_SCOPE_AGENT)
                     < (unsigned)t
                 && spin < (1 << 16)){
            __builtin_amdgcn_s_sleep(1);
            ++spin;
          }
        }
      }
      if (tid == 0) __builtin_amdgcn_fence(__ATOMIC_ACQUIRE, "agent"); // inv stale hin
      __syncthreads();
    }
  }
}

// ---- column stats (sum, sumsq), stage 1 ----
template<int C>
__global__ __launch_bounds__(256) void stats1(
    const unsigned short* __restrict__ X, float* __restrict__ psum, float* __restrict__ psq)
{
  int col = blockIdx.x * 256 + threadIdx.x;
  int r0 = blockIdx.y * 256;
  float s = 0.f, q = 0.f;
  for (int r = r0; r < r0 + 256; r++){
    float v = b2f(X[(size_t)r * C + col]);
    s += v; q += v * v;
  }
  psum[(size_t)blockIdx.y * C + col] = s;
  psq [(size_t)blockIdx.y * C + col] = q;
}

__global__ __launch_bounds__(256) void stats2(
    const float* __restrict__ psum, const float* __restrict__ psq,
    const float* __restrict__ g, const float* __restrict__ b,
    float* __restrict__ alpha, float* __restrict__ beta, int C)
{
  int c = blockIdx.x * 256 + threadIdx.x;
  if (c >= C) return;
  float s = 0.f, q = 0.f;
  for (int i = 0; i < 256; i++){ s += psum[(size_t)i * C + c]; q += psq[(size_t)i * C + c]; }
  float m = s * (1.f / 65536.f);
  float var = q * (1.f / 65536.f) - m * m; if (var < 0.f) var = 0.f;
  float a = g[c] * rsqrtf(var + 1e-5f);
  alpha[c] = a; beta[c] = b[c] - m * a;
}

// ---- fold BN into weights ----
template<int K>
__global__ __launch_bounds__(256) void foldk(
    const float* __restrict__ W, const float* __restrict__ bias,
    const float* __restrict__ alpha, const float* __restrict__ beta,
    unsigned short* __restrict__ Wb, float* __restrict__ bp, int rows)
{
  __shared__ float red[4];
  int o = blockIdx.x, t = threadIdx.x;
  float acc = 0.f;
  if (o < rows){
    for (int j = t; j < K; j += 256){
      float wv = W[(size_t)o * K + j];
      acc += beta[j] * wv;
      Wb[(size_t)o * K + j] = f2b(wv * alpha[j]);
    }
  } else {
    for (int j = t; j < K; j += 256) Wb[(size_t)o * K + j] = 0;
  }
  for (int off = 32; off > 0; off >>= 1) acc += __shfl_down(acc, off, 64);
  if ((t & 63) == 0) red[t >> 6] = acc;
  __syncthreads();
  if (t == 0) bp[o] = (o < rows ? bias[o] : 0.f) + red[0] + red[1] + red[2] + red[3];
}

// ---- final softmax with raw-reshape index mixing ----
__global__ __launch_bounds__(256) void softmax_k(
    const unsigned short* __restrict__ o3p, float* __restrict__ out)
{
  __shared__ unsigned short tile[25600];
  int b = blockIdx.x, t = threadIdx.x;
  const unsigned short* src = o3p + (size_t)b * 256 * 128;
  for (int i = t; i < 25600; i += 256){
    int rr = i / 100, nc = i - rr * 100;
    tile[i] = src[rr * 128 + nc];
  }
  __syncthreads();
  int v = t;
  float mx = -1e30f;
  for (int u = 0; u < 100; u++) mx = fmaxf(mx, b2f(tile[u * 256 + v]));
  float s = 0.f;
  for (int u = 0; u < 100; u++) s += __expf(b2f(tile[u * 256 + v]) - mx);
  float inv = 1.f / s;
  float* dst = out + (size_t)b * 25600;
  for (int u = 0; u < 100; u++)
    dst[u * 256 + v] = __expf(b2f(tile[u * 256 + v]) - mx) * inv;
}

extern "C" void kernel_launch(void* const* d_in, const int* in_sizes, int n_in,
                              void* d_out, int out_size, void* d_ws, size_t ws_size,
                              hipStream_t stream)
{
  (void)in_sizes; (void)n_in;
  const float* z     = (const float*)d_in[0];
  const float* Wzh   = (const float*)d_in[1];
  const float* bzh   = (const float*)d_in[2];
  const float* Wzc   = (const float*)d_in[3];
  const float* bzc   = (const float*)d_in[4];
  const float* g_bnzh= (const float*)d_in[5];
  const float* b_bnzh= (const float*)d_in[6];
  const float* g_bnzc= (const float*)d_in[7];
  const float* b_bnzc= (const float*)d_in[8];
  const float* Wih   = (const float*)d_in[9];
  const float* bih   = (const float*)d_in[10];
  const float* Whh   = (const float*)d_in[11];
  const float* bhh   = (const float*)d_in[12];
  const float* g_bn0 = (const float*)d_in[13];
  const float* b_bn0 = (const float*)d_in[14];
  const float* W1    = (const float*)d_in[15];
  const float* b1    = (const float*)d_in[16];
  const float* g_bn1 = (const float*)d_in[17];
  const float* b_bn1 = (const float*)d_in[18];
  const float* W2    = (const float*)d_in[19];
  const float* b2    = (const float*)d_in[20];
  const float* g_bn2 = (const float*)d_in[21];
  const float* b_bn2 = (const float*)d_in[22];
  const float* W3    = (const float*)d_in[23];
  const float* b3    = (const float*)d_in[24];
  const float* go    = (const float*)d_in[25];

  char* base = (char*)d_ws;
  size_t off = 0;
  auto alloc = [&](size_t bytes)->char*{
    char* p = base + off;
    off = (off + bytes + 255) & ~(size_t)255;
    return p;
  };
  const size_t MB = 1024 * 1024;

  unsigned short* ys = (unsigned short*)alloc(128 * MB);  // [b*1024+h][256] bf16
  unsigned short* o1 = (unsigned short*)alloc(64 * MB);   // [65536][512] bf16
  char* zone = alloc(32 * MB);                            // dead after LSTM; o2 overlays
  unsigned short* Wsum_p = (unsigned short*)(zone);            // 8 MB
  unsigned short* Whh_b  = (unsigned short*)(zone + 8 * MB);   // 8 MB
  float*          gates0 = (float*)(zone + 16 * MB);           // 4 MB
  // persistent-small region
  float* zh_raw = (float*)alloc(1 * MB);
  float* zc_raw = (float*)alloc(1 * MB);
  float* bias_sp = (float*)alloc(16384);
  float* bias0   = (float*)alloc(16384);
  unsigned short* zh_b  = (unsigned short*)alloc((size_t)256 * 1024 * 2);
  unsigned short* hbuf0 = (unsigned short*)alloc((size_t)256 * 1024 * 2);
  unsigned short* hbuf1 = (unsigned short*)alloc((size_t)256 * 1024 * 2);
  float* c_f    = (float*)alloc((size_t)256 * 1024 * 4);
  float* psum   = (float*)alloc(1 * MB);
  float* psq    = (float*)alloc(1 * MB);
  float* alpha0 = (float*)alloc(4096); float* beta0 = (float*)alloc(4096);
  float* alpha1 = (float*)alloc(4096); float* beta1 = (float*)alloc(4096);
  float* alpha2 = (float*)alloc(4096); float* beta2 = (float*)alloc(4096);
  unsigned short* W1b = (unsigned short*)alloc((size_t)512 * 1024 * 2);
  unsigned short* W2b = (unsigned short*)alloc((size_t)256 * 512 * 2);
  unsigned short* W3b = (unsigned short*)alloc((size_t)128 * 256 * 2);
  float* b1p = (float*)alloc(4096);
  float* b2p = (float*)alloc(4096);
  float* b3p = (float*)alloc(4096);
  unsigned int* arr = (unsigned int*)alloc(32768);   // 256 arrival lines, 128B stride
  unsigned int* rel = (unsigned int*)alloc(32768);   // 256 release lines, 128B stride
  unsigned short* o2  = (unsigned short*)zone;  // 32 MB overlays dead zone
  unsigned short* o3p = o1;                     // 16 MB overlays dead o1

  if (off > ws_size){
    zerofill<<<(out_size + 255) / 256, 256, 0, stream>>>((float*)d_out, out_size);
    return;
  }

  zerofill<<<64, 256, 0, stream>>>((float*)arr, 16384);  // arr + rel (contiguous)
  prep_w<<<16384, 256, 0, stream>>>(Wih, Whh, bih, bhh, Wsum_p, Whh_b, bias_sp);
  prep_b0<<<4096, 256, 0, stream>>>(Wih, go, bih, bhh, bias0);
  zproj<<<1024, 256, 0, stream>>>(z, Wzh, bzh, Wzc, bzc, zh_raw, zc_raw);
  bn_init<<<1024, 256, 0, stream>>>(zh_raw, zc_raw, g_bnzh, b_bnzh, g_bnzc, b_bnzc, zh_b, c_f);

  // step 0: gates0 = zh @ Whh^T + bias0(go-term folded); then cell
  gemm_bt2<1024, 0, 0><<<dim3(32, 4), 256, 0, stream>>>(zh_b, Whh_b, bias0, gates0, 4096);
  lstm_cell0<<<1024, 256, 0, stream>>>(gates0, c_f, hbuf0);

  // steps 1..255 in one persistent kernel (256 blocks x 512 threads, 8 waves/CU)
  lstm_persist<<<NBLK, 512, 0, stream>>>(Wsum_p, bias_sp, hbuf0, hbuf1, c_f, ys, arr, rel);

  stats1<1024><<<dim3(4, 256), 256, 0, stream>>>(ys, psum, psq);
  stats2<<<4, 256, 0, stream>>>(psum, psq, g_bn0, b_bn0, alpha0, beta0, 1024);
  foldk<1024><<<512, 256, 0, stream>>>(W1, b1, alpha0, beta0, W1b, b1p, 512);
  gemm_bt2<1024, 1, 1><<<dim3(4, 1024), 256, 0, stream>>>(ys, W1b, b1p, o1, 512);

  stats1<512><<<dim3(2, 256), 256, 0, stream>>>(o1, psum, psq);
  stats2<<<2, 256, 0, stream>>>(psum, psq, g_bn1, b_bn1, alpha1, beta1, 512);
  foldk<512><<<256, 256, 0, stream>>>(W2, b2, alpha1, beta1, W2b, b2p, 256);
  gemm_bt2<512, 1, 1><<<dim3(2, 1024), 256, 0, stream>>>(o1, W2b, b2p, o2, 256);

  stats1<256><<<dim3(1, 256), 256, 0, stream>>>(o2, psum, psq);
  stats2<<<1, 256, 0, stream>>>(psum, psq, g_bn2, b_bn2, alpha2, beta2, 256);
  foldk<256><<<128, 256, 0, stream>>>(W3, b3, alpha2, beta2, W3b, b3p, 100);
  gemm_bt2<256, 0, 1><<<dim3(1, 1024), 256, 0, stream>>>(o2, W3b, b3p, o3p, 128);

  softmax_k<<<256, 256, 0, stream>>>(o3p, (float*)d_out);
}